// Round 2
// baseline (1932.345 us; speedup 1.0000x reference)
//
#include <hip/hip_runtime.h>
#include <hip/hip_bf16.h>

typedef unsigned short u16;
typedef unsigned int u32;

#define DEVI __device__ __forceinline__

constexpr int BB = 8, HHc = 56, WWc = 56, DIMC = 384, NHC = 8, HDC = 48, WSZ = 14;
constexpr int NTOK = BB * HHc * WWc;          // 25088
constexpr int HIDC = 4 * DIMC;                // 1536
constexpr float EPSF = 1e-5f;
constexpr float SCALEF = 0.14433756729740643f;   // 48^-0.5

// ---- bf16 helpers (raw ushort view) ----
DEVI float b2f(u16 u) { u32 x = ((u32)u) << 16; float f; __builtin_memcpy(&f, &x, 4); return f; }
DEVI u16 f2b(float f) {
  u32 x; __builtin_memcpy(&x, &f, 4);
  u32 r = (x >> 16) & 1u; x += 0x7fffu + r;
  return (u16)(x >> 16);
}

DEVI float wred_sum(float v) {
  #pragma unroll
  for (int o = 32; o; o >>= 1) v += __shfl_xor(v, o);
  return v;
}

// ---- LayerNorm over 384: f32 in -> bf16 out (one wave per token) ----
__global__ __launch_bounds__(256)
void ln384_kernel(const float* __restrict__ x, const float* __restrict__ w,
                  const float* __restrict__ b, u16* __restrict__ out) {
  int wave = threadIdx.x >> 6, lane = threadIdx.x & 63;
  int tok = blockIdx.x * 4 + wave;
  if (tok >= NTOK) return;
  const float* xr = x + (size_t)tok * DIMC;
  float v[6]; float s = 0.f, ss = 0.f;
  #pragma unroll
  for (int i = 0; i < 6; ++i) {
    v[i] = xr[lane + i * 64];
    s += v[i]; ss += v[i] * v[i];
  }
  s = wred_sum(s); ss = wred_sum(ss);
  float mean = s * (1.f / 384.f);
  float var = ss * (1.f / 384.f) - mean * mean;
  float inv = rsqrtf(var + EPSF);
  u16* orow = out + (size_t)tok * DIMC;
  #pragma unroll
  for (int i = 0; i < 6; ++i) {
    int c = lane + i * 64;
    orow[c] = f2b((v[i] - mean) * inv * w[c] + b[c]);
  }
}

// ---- Tiled GEMM: C[M,N] = A(bf16)[M,K] @ W(f32)[K,N] + bias, epilogues ----
// MODE 0: scatter bf16 to qkv layout [3, B*NH, 56*56, 48]
// MODE 1: f32 out = v + res (f32 residual), row-major
// MODE 2: bf16 out = GELU(exact)(v), row-major
template<int MODE>
__global__ __launch_bounds__(256)
void gemm_kernel(const u16* __restrict__ A, const float* __restrict__ W,
                 const float* __restrict__ bias, const float* __restrict__ res,
                 void* __restrict__ outv, int M, int N, int K) {
  __shared__ float As[16][64];   // As[k][m]
  __shared__ float Bs[16][64];   // Bs[k][n]
  int tid = threadIdx.x;
  int tx = tid & 15, ty = tid >> 4;
  int row0 = blockIdx.x * 64, col0 = blockIdx.y * 64;
  int arow = tid >> 2;           // 0..63
  int ak = (tid & 3) * 4;        // 0,4,8,12
  int bk = tid >> 4;             // 0..15
  int bn4 = (tid & 15) * 4;      // 0..60
  float acc[4][4] = {};
  for (int k0 = 0; k0 < K; k0 += 16) {
    ushort4 av = *reinterpret_cast<const ushort4*>(A + (size_t)(row0 + arow) * K + k0 + ak);
    As[ak + 0][arow] = b2f(av.x);
    As[ak + 1][arow] = b2f(av.y);
    As[ak + 2][arow] = b2f(av.z);
    As[ak + 3][arow] = b2f(av.w);
    float4 bv = *reinterpret_cast<const float4*>(W + (size_t)(k0 + bk) * N + col0 + bn4);
    Bs[bk][bn4 + 0] = bv.x;
    Bs[bk][bn4 + 1] = bv.y;
    Bs[bk][bn4 + 2] = bv.z;
    Bs[bk][bn4 + 3] = bv.w;
    __syncthreads();
    #pragma unroll
    for (int k = 0; k < 16; ++k) {
      float4 a = *reinterpret_cast<const float4*>(&As[k][ty * 4]);
      float4 b = *reinterpret_cast<const float4*>(&Bs[k][tx * 4]);
      acc[0][0] += a.x * b.x; acc[0][1] += a.x * b.y; acc[0][2] += a.x * b.z; acc[0][3] += a.x * b.w;
      acc[1][0] += a.y * b.x; acc[1][1] += a.y * b.y; acc[1][2] += a.y * b.z; acc[1][3] += a.y * b.w;
      acc[2][0] += a.z * b.x; acc[2][1] += a.z * b.y; acc[2][2] += a.z * b.z; acc[2][3] += a.z * b.w;
      acc[3][0] += a.w * b.x; acc[3][1] += a.w * b.y; acc[3][2] += a.w * b.z; acc[3][3] += a.w * b.w;
    }
    __syncthreads();
  }
  int cg0 = col0 + tx * 4;
  float bsv[4];
  #pragma unroll
  for (int j = 0; j < 4; ++j) bsv[j] = bias[cg0 + j];
  #pragma unroll
  for (int i = 0; i < 4; ++i) {
    int r = row0 + ty * 4 + i;
    #pragma unroll
    for (int j = 0; j < 4; ++j) {
      float v = acc[i][j] + bsv[j];
      int cg = cg0 + j;
      if constexpr (MODE == 0) {
        u16* out = (u16*)outv;
        int s = cg / DIMC; int rem = cg - s * DIMC;
        int nh = rem / HDC; int c = rem - nh * HDC;
        int b = r / 3136; int hw = r - b * 3136;
        out[(((size_t)(s * 64 + b * 8 + nh)) * 3136 + hw) * 48 + c] = f2b(v);
      } else if constexpr (MODE == 1) {
        float* out = (float*)outv;
        size_t idx = (size_t)r * N + cg;
        out[idx] = v + res[idx];
      } else {
        u16* out = (u16*)outv;
        size_t idx = (size_t)r * N + cg;
        out[idx] = f2b(0.5f * v * (1.0f + erff(v * 0.70710678118654752440f)));
      }
    }
  }
}

// ---- depthwise 3x3 conv (pad 1) + LayerNorm over 48 channels ----
// bf16 in, f32 weights/params, bf16 out. one wave per pixel.
__global__ __launch_bounds__(256)
void convln_kernel(const u16* __restrict__ qkv,
                   const float* __restrict__ wq, const float* __restrict__ wk, const float* __restrict__ wv,
                   const float* __restrict__ gq, const float* __restrict__ bq,
                   const float* __restrict__ gk, const float* __restrict__ bk,
                   const float* __restrict__ gv, const float* __restrict__ bv,
                   u16* __restrict__ out) {
  int wave = threadIdx.x >> 6, lane = threadIdx.x & 63;
  int pix = blockIdx.x * 4 + wave;          // [0, 3*64*3136)
  int sb = pix / 3136;                      // s*64 + bnh
  int hw = pix - sb * 3136;
  int s = sb >> 6;
  int h = hw / 56, w = hw - h * 56;
  const float* wgt = (s == 0) ? wq : ((s == 1) ? wk : wv);
  const float* gam = (s == 0) ? gq : ((s == 1) ? gk : gv);
  const float* bet = (s == 0) ? bq : ((s == 1) ? bk : bv);
  float acc = 0.f;
  int c = lane;
  if (c < 48) {
    const u16* base = qkv + (size_t)sb * 3136 * 48;
    #pragma unroll
    for (int dy = -1; dy <= 1; ++dy) {
      int hh = h + dy;
      if (hh < 0 || hh >= 56) continue;
      #pragma unroll
      for (int dx = -1; dx <= 1; ++dx) {
        int ww = w + dx;
        if (ww < 0 || ww >= 56) continue;
        acc += b2f(base[(size_t)(hh * 56 + ww) * 48 + c]) *
               wgt[((dy + 1) * 3 + (dx + 1)) * 48 + c];
      }
    }
  }
  float sv = (c < 48) ? acc : 0.f;
  float sum = wred_sum(sv);
  float ssq = wred_sum(sv * sv);
  float mean = sum * (1.f / 48.f);
  float var = ssq * (1.f / 48.f) - mean * mean;
  float inv = rsqrtf(var + EPSF);
  if (c < 48)
    out[(size_t)pix * 48 + c] = f2b((acc - mean) * inv * gam[c] + bet[c]);
}

// ---- window attention: one block per window (1024 windows) ----
// K in LDS f32, V in LDS bf16; per-query thread 2-pass softmax
__global__ __launch_bounds__(256)
void attn_kernel(const u16* __restrict__ qkvc, const float* __restrict__ rel_h,
                 const float* __restrict__ rel_w, u16* __restrict__ obuf) {
  __shared__ float kk[196][48];
  __shared__ u16 vvs[196][48];
  int wid = blockIdx.x;
  int bnh = wid >> 4, wrem = wid & 15, wh = wrem >> 2, wwn = wrem & 3;
  int tid = threadIdx.x;
  size_t kbase = ((size_t)(64 + bnh) * 3136) * 48;
  size_t vbase = ((size_t)(128 + bnh) * 3136) * 48;
  for (int i = tid; i < 196 * 48; i += 256) {
    int r = i / 48, c = i - r * 48;
    int h = wh * 14 + r / 14, w = wwn * 14 + (r % 14);
    size_t g = (size_t)(h * 56 + w) * 48 + c;
    kk[r][c] = b2f(qkvc[kbase + g]);
    vvs[r][c] = qkvc[vbase + g];
  }
  __syncthreads();
  if (tid >= 196) return;
  int qh = tid / 14, qw = tid - qh * 14;
  int h = wh * 14 + qh, w = wwn * 14 + qw;
  size_t qaddr = ((size_t)bnh * 3136 + h * 56 + w) * 48;
  float qf[48];
  #pragma unroll
  for (int c = 0; c < 48; ++c) qf[c] = b2f(qkvc[qaddr + c]);
  // decomposed rel-pos bias (uses UNscaled q)
  float bh[14], bw[14];
  for (int kh = 0; kh < 14; ++kh) {
    const float* rp = rel_h + (qh - kh + 13) * 48;
    const float* rpw = rel_w + (qw - kh + 13) * 48;
    float s1 = 0.f, s2 = 0.f;
    #pragma unroll
    for (int c = 0; c < 48; ++c) { s1 += qf[c] * rp[c]; s2 += qf[c] * rpw[c]; }
    bh[kh] = s1; bw[kh] = s2;
  }
  // pass 1: row max
  float m = -1e30f;
  {
    int kh = 0, kw = 0;
    for (int k = 0; k < 196; ++k) {
      const float4* kr = reinterpret_cast<const float4*>(kk[k]);
      float s = 0.f;
      #pragma unroll
      for (int c4 = 0; c4 < 12; ++c4) {
        float4 kv = kr[c4];
        s += qf[c4 * 4 + 0] * kv.x + qf[c4 * 4 + 1] * kv.y + qf[c4 * 4 + 2] * kv.z + qf[c4 * 4 + 3] * kv.w;
      }
      s = s * SCALEF + bh[kh] + bw[kw];
      m = fmaxf(m, s);
      if (++kw == 14) { kw = 0; ++kh; }
    }
  }
  // pass 2: exp + PV accumulate
  float den = 0.f;
  float o[48] = {};
  {
    int kh = 0, kw = 0;
    for (int k = 0; k < 196; ++k) {
      const float4* kr = reinterpret_cast<const float4*>(kk[k]);
      float s = 0.f;
      #pragma unroll
      for (int c4 = 0; c4 < 12; ++c4) {
        float4 kv = kr[c4];
        s += qf[c4 * 4 + 0] * kv.x + qf[c4 * 4 + 1] * kv.y + qf[c4 * 4 + 2] * kv.z + qf[c4 * 4 + 3] * kv.w;
      }
      s = s * SCALEF + bh[kh] + bw[kw];
      float p = expf(s - m);
      den += p;
      const ushort4* vr = reinterpret_cast<const ushort4*>(vvs[k]);
      #pragma unroll
      for (int c4 = 0; c4 < 12; ++c4) {
        ushort4 vv4 = vr[c4];
        o[c4 * 4 + 0] += p * b2f(vv4.x);
        o[c4 * 4 + 1] += p * b2f(vv4.y);
        o[c4 * 4 + 2] += p * b2f(vv4.z);
        o[c4 * 4 + 3] += p * b2f(vv4.w);
      }
      if (++kw == 14) { kw = 0; ++kh; }
    }
  }
  float rden = 1.f / den;
  int b = bnh >> 3, nh = bnh & 7;
  u16* op = obuf + ((size_t)(b * 56 + h) * 56 + w) * 384 + nh * 48;
  #pragma unroll
  for (int c = 0; c < 48; ++c) op[c] = f2b(o[c] * rden + qf[c]);   // + ori_q residual
}

extern "C" void kernel_launch(void* const* d_in, const int* in_sizes, int n_in,
                              void* d_out, int out_size, void* d_ws, size_t ws_size,
                              hipStream_t stream) {
  const float* x1      = (const float*)d_in[0];
  const float* x2      = (const float*)d_in[1];
  const float* norm1_w = (const float*)d_in[2];
  const float* norm1_b = (const float*)d_in[3];
  const float* qkv_w   = (const float*)d_in[4];
  const float* qkv_b   = (const float*)d_in[5];
  const float* poolq_w = (const float*)d_in[6];
  const float* poolk_w = (const float*)d_in[7];
  const float* poolv_w = (const float*)d_in[8];
  const float* nq_w    = (const float*)d_in[9];
  const float* nq_b    = (const float*)d_in[10];
  const float* nk_w    = (const float*)d_in[11];
  const float* nk_b    = (const float*)d_in[12];
  const float* nv_w    = (const float*)d_in[13];
  const float* nv_b    = (const float*)d_in[14];
  const float* rel_h   = (const float*)d_in[15];
  const float* rel_w   = (const float*)d_in[16];
  const float* proj_w  = (const float*)d_in[17];
  const float* proj_b  = (const float*)d_in[18];
  const float* norm2_w = (const float*)d_in[19];
  const float* norm2_b = (const float*)d_in[20];
  const float* fc1_w   = (const float*)d_in[21];
  const float* fc1_b   = (const float*)d_in[22];
  const float* fc2_w   = (const float*)d_in[23];
  const float* fc2_b   = (const float*)d_in[24];

  // ws overlay (u16 units). Peak = 57,802,752 u16 = 115.6 MB
  u16* ws   = (u16*)d_ws;
  u16* qkv  = ws;                  // [0, 28901376)   qkv bf16, [3,64,3136,48] layout
  u16* xn   = ws + 28901376;       // [28901376, 38535168)  LN(x1) bf16
  u16* qkvc = ws + 28901376;       // [28901376, 57802752)  post conv+LN bf16 (overwrites xn)
  u16* obuf = ws;                  // [0, 9633792)    attn out bf16 [B,H,W,384] (overwrites qkv)
  u16* h1   = ws;                  // [0, 38535168)   gelu(fc1) bf16 (overwrites obuf)
  u16* yn   = ws + 48168960;       // [48168960, 57802752)  LN(y1) bf16
  float* y1 = (float*)d_out;       // first 9633792 f32
  float* y2 = y1 + 9633792;

  // 1. xn = LN(x1)
  ln384_kernel<<<NTOK / 4, 256, 0, stream>>>(x1, norm1_w, norm1_b, xn);
  // 2. qkv = xn @ qkv_w + qkv_b  (scattered layout)
  gemm_kernel<0><<<dim3(392, 18), 256, 0, stream>>>(xn, qkv_w, qkv_b, nullptr, qkv, NTOK, 1152, 384);
  // 3. q/k/v = LN(dwconv3x3(qkv))
  convln_kernel<<<3 * 64 * 3136 / 4, 256, 0, stream>>>(qkv, poolq_w, poolk_w, poolv_w,
                                                       nq_w, nq_b, nk_w, nk_b, nv_w, nv_b, qkvc);
  // 4. window attention (+ ori_q residual), permuted to [B,H,W,384]
  attn_kernel<<<1024, 256, 0, stream>>>(qkvc, rel_h, rel_w, obuf);
  // 5. y1 = x1 + obuf @ proj_w + proj_b
  gemm_kernel<1><<<dim3(392, 6), 256, 0, stream>>>(obuf, proj_w, proj_b, x1, y1, NTOK, 384, 384);
  // 6. yn = LN(y1)
  ln384_kernel<<<NTOK / 4, 256, 0, stream>>>(y1, norm2_w, norm2_b, yn);
  // 7. h1 = gelu(yn @ fc1_w + fc1_b)
  gemm_kernel<2><<<dim3(392, 24), 256, 0, stream>>>(yn, fc1_w, fc1_b, nullptr, h1, NTOK, 1536, 384);
  // 8. y2 = x2 + h1 @ fc2_w + fc2_b
  gemm_kernel<1><<<dim3(392, 6), 256, 0, stream>>>(h1, fc2_w, fc2_b, x2, y2, NTOK, 384, 1536);
}

// Round 3
// 948.856 us; speedup vs baseline: 2.0365x; 2.0365x over previous
//
#include <hip/hip_runtime.h>
#include <hip/hip_bf16.h>

typedef unsigned short u16;
typedef unsigned int u32;

#define DEVI __device__ __forceinline__

constexpr int BB = 8, HHc = 56, WWc = 56, DIMC = 384, NHC = 8, HDC = 48, WSZ = 14;
constexpr int NTOK = BB * HHc * WWc;          // 25088
constexpr int HIDC = 4 * DIMC;                // 1536
constexpr float EPSF = 1e-5f;
constexpr float SCALEF = 0.14433756729740643f;   // 48^-0.5

typedef short bf16x8 __attribute__((ext_vector_type(8)));
typedef float f32x4 __attribute__((ext_vector_type(4)));

// ---- bf16 helpers (raw ushort view) ----
DEVI float b2f(u16 u) { u32 x = ((u32)u) << 16; float f; __builtin_memcpy(&f, &x, 4); return f; }
DEVI u16 f2b(float f) {
  u32 x; __builtin_memcpy(&x, &f, 4);
  u32 r = (x >> 16) & 1u; x += 0x7fffu + r;
  return (u16)(x >> 16);
}

DEVI float wred_sum(float v) {
  #pragma unroll
  for (int o = 32; o; o >>= 1) v += __shfl_xor(v, o);
  return v;
}

// ---- weight convert f32 [K][N] -> bf16 [N][K] (transpose) ----
__global__ __launch_bounds__(256)
void wcvt_kernel(const float* __restrict__ in, u16* __restrict__ out, int K, int N) {
  int id = blockIdx.x * 256 + threadIdx.x;
  if (id >= K * N) return;
  int n = id / K, k = id - n * K;
  out[id] = f2b(in[(size_t)k * N + n]);
}

// ---- LayerNorm over 384: f32 in -> bf16 out (one wave per token) ----
__global__ __launch_bounds__(256)
void ln384_kernel(const float* __restrict__ x, const float* __restrict__ w,
                  const float* __restrict__ b, u16* __restrict__ out) {
  int wave = threadIdx.x >> 6, lane = threadIdx.x & 63;
  int tok = blockIdx.x * 4 + wave;
  if (tok >= NTOK) return;
  const float* xr = x + (size_t)tok * DIMC;
  float v[6]; float s = 0.f, ss = 0.f;
  #pragma unroll
  for (int i = 0; i < 6; ++i) {
    v[i] = xr[lane + i * 64];
    s += v[i]; ss += v[i] * v[i];
  }
  s = wred_sum(s); ss = wred_sum(ss);
  float mean = s * (1.f / 384.f);
  float var = ss * (1.f / 384.f) - mean * mean;
  float inv = rsqrtf(var + EPSF);
  u16* orow = out + (size_t)tok * DIMC;
  #pragma unroll
  for (int i = 0; i < 6; ++i) {
    int c = lane + i * 64;
    orow[c] = f2b((v[i] - mean) * inv * w[c] + b[c]);
  }
}

// ---- MFMA GEMM: C[M,N] = A(bf16)[M,K] @ Wt(bf16,[N][K])^T + bias ----
// 128x128 tile, BK=32, 4 waves, each wave 64x64 (4x4 frags of 16x16x32).
// MODE 0: scatter bf16 to qkv layout [3, B*NH, 56*56, 48]
// MODE 1: f32 out = v + res (f32 residual), row-major
// MODE 2: bf16 out = GELU(exact)(v), row-major
template<int MODE>
__global__ __launch_bounds__(256)
void mgemm_kernel(const u16* __restrict__ A, const u16* __restrict__ Wt,
                  const float* __restrict__ bias, const float* __restrict__ res,
                  void* __restrict__ outv, int M, int N, int K) {
  constexpr int LDT = 40;                       // padded k-stride (elements)
  __shared__ __attribute__((aligned(16))) u16 As[128 * LDT];
  __shared__ __attribute__((aligned(16))) u16 Bs[128 * LDT];
  int tid = threadIdx.x;
  int wave = tid >> 6, lane = tid & 63;
  int wr = wave >> 1, wc = wave & 1;
  int bm0 = blockIdx.x * 128, bn0 = blockIdx.y * 128;
  int srow = tid >> 1, shalf = tid & 1;         // staging: row, k-half(16 elems)
  const u16* ag = A  + (size_t)(bm0 + srow) * K + shalf * 16;
  const u16* bg = Wt + (size_t)(bn0 + srow) * K + shalf * 16;
  u16* asw = As + srow * LDT + shalf * 16;
  u16* bsw = Bs + srow * LDT + shalf * 16;
  int q = lane >> 4, r16 = lane & 15;
  const u16* ar = As + (wr * 64 + r16) * LDT + q * 8;
  const u16* br = Bs + (wc * 64 + r16) * LDT + q * 8;
  f32x4 acc[4][4] = {};
  for (int k0 = 0; k0 < K; k0 += 32) {
    uint4 av  = *reinterpret_cast<const uint4*>(ag + k0);
    uint4 av2 = *reinterpret_cast<const uint4*>(ag + k0 + 8);
    uint4 bv  = *reinterpret_cast<const uint4*>(bg + k0);
    uint4 bv2 = *reinterpret_cast<const uint4*>(bg + k0 + 8);
    __syncthreads();
    *reinterpret_cast<uint4*>(asw)     = av;
    *reinterpret_cast<uint4*>(asw + 8) = av2;
    *reinterpret_cast<uint4*>(bsw)     = bv;
    *reinterpret_cast<uint4*>(bsw + 8) = bv2;
    __syncthreads();
    bf16x8 af[4], bf[4];
    #pragma unroll
    for (int f = 0; f < 4; ++f) {
      af[f] = *reinterpret_cast<const bf16x8*>(ar + f * 16 * LDT);
      bf[f] = *reinterpret_cast<const bf16x8*>(br + f * 16 * LDT);
    }
    #pragma unroll
    for (int fm = 0; fm < 4; ++fm)
      #pragma unroll
      for (int fn = 0; fn < 4; ++fn)
        acc[fm][fn] = __builtin_amdgcn_mfma_f32_16x16x32_bf16(af[fm], bf[fn], acc[fm][fn], 0, 0, 0);
  }
  // epilogue: D layout col=lane&15, row=(lane>>4)*4+j
  int c0 = bn0 + wc * 64 + r16;
  int r0 = bm0 + wr * 64 + q * 4;
  #pragma unroll
  for (int fm = 0; fm < 4; ++fm) {
    #pragma unroll
    for (int fn = 0; fn < 4; ++fn) {
      int c = c0 + fn * 16;
      float bsv = bias[c];
      #pragma unroll
      for (int j = 0; j < 4; ++j) {
        int r = r0 + fm * 16 + j;
        float v = acc[fm][fn][j] + bsv;
        if constexpr (MODE == 0) {
          u16* out = (u16*)outv;
          int s = c / DIMC; int rem = c - s * DIMC;
          int nh = rem / HDC; int ch = rem - nh * HDC;
          int b = r / 3136; int hw = r - b * 3136;
          out[(((size_t)(s * 64 + b * 8 + nh)) * 3136 + hw) * 48 + ch] = f2b(v);
        } else if constexpr (MODE == 1) {
          float* out = (float*)outv;
          size_t idx = (size_t)r * N + c;
          out[idx] = v + res[idx];
        } else {
          u16* out = (u16*)outv;
          size_t idx = (size_t)r * N + c;
          out[idx] = f2b(0.5f * v * (1.0f + erff(v * 0.70710678118654752440f)));
        }
      }
    }
  }
}

// ---- depthwise 3x3 conv (pad 1) + LayerNorm over 48 channels ----
__global__ __launch_bounds__(256)
void convln_kernel(const u16* __restrict__ qkv,
                   const float* __restrict__ wq, const float* __restrict__ wk, const float* __restrict__ wv,
                   const float* __restrict__ gq, const float* __restrict__ bq,
                   const float* __restrict__ gk, const float* __restrict__ bk,
                   const float* __restrict__ gv, const float* __restrict__ bv,
                   u16* __restrict__ out) {
  int wave = threadIdx.x >> 6, lane = threadIdx.x & 63;
  int pix = blockIdx.x * 4 + wave;          // [0, 3*64*3136)
  int sb = pix / 3136;                      // s*64 + bnh
  int hw = pix - sb * 3136;
  int s = sb >> 6;
  int h = hw / 56, w = hw - h * 56;
  const float* wgt = (s == 0) ? wq : ((s == 1) ? wk : wv);
  const float* gam = (s == 0) ? gq : ((s == 1) ? gk : gv);
  const float* bet = (s == 0) ? bq : ((s == 1) ? bk : bv);
  float acc = 0.f;
  int c = lane;
  if (c < 48) {
    const u16* base = qkv + (size_t)sb * 3136 * 48;
    #pragma unroll
    for (int dy = -1; dy <= 1; ++dy) {
      int hh = h + dy;
      if (hh < 0 || hh >= 56) continue;
      #pragma unroll
      for (int dx = -1; dx <= 1; ++dx) {
        int ww = w + dx;
        if (ww < 0 || ww >= 56) continue;
        acc += b2f(base[(size_t)(hh * 56 + ww) * 48 + c]) *
               wgt[((dy + 1) * 3 + (dx + 1)) * 48 + c];
      }
    }
  }
  float sv = (c < 48) ? acc : 0.f;
  float sum = wred_sum(sv);
  float ssq = wred_sum(sv * sv);
  float mean = sum * (1.f / 48.f);
  float var = ssq * (1.f / 48.f) - mean * mean;
  float inv = rsqrtf(var + EPSF);
  if (c < 48)
    out[(size_t)pix * 48 + c] = f2b((acc - mean) * inv * gam[c] + bet[c]);
}

// ---- window attention: one block per window (1024 windows) ----
// one-pass online softmax (deferred rescale, THR=20); K f32 in LDS,
// V bf16 from global (all lanes read same row -> L1 broadcast)
__global__ __launch_bounds__(256)
void attn_kernel(const u16* __restrict__ qkvc, const float* __restrict__ rel_h,
                 const float* __restrict__ rel_w, u16* __restrict__ obuf) {
  __shared__ float kk[196][48];
  int wid = blockIdx.x;
  int bnh = wid >> 4, wrem = wid & 15, wh = wrem >> 2, wwn = wrem & 3;
  int tid = threadIdx.x;
  size_t kbase = ((size_t)(64 + bnh) * 3136) * 48;
  const u16* vwin = qkvc + ((size_t)(128 + bnh) * 3136) * 48;
  for (int i = tid; i < 196 * 48; i += 256) {
    int r = i / 48, c = i - r * 48;
    int h = wh * 14 + r / 14, w = wwn * 14 + (r % 14);
    kk[r][c] = b2f(qkvc[kbase + (size_t)(h * 56 + w) * 48 + c]);
  }
  __syncthreads();
  if (tid >= 196) return;
  int qh = tid / 14, qw = tid - qh * 14;
  int h = wh * 14 + qh, w = wwn * 14 + qw;
  const u16* qp = qkvc + ((size_t)bnh * 3136 + h * 56 + w) * 48;
  float qf[48];
  #pragma unroll
  for (int c = 0; c < 48; ++c) qf[c] = b2f(qp[c]);
  // decomposed rel-pos bias (uses UNscaled q)
  float bh[14], bw[14];
  for (int kh = 0; kh < 14; ++kh) {
    const float* rp  = rel_h + (qh - kh + 13) * 48;
    const float* rpw = rel_w + (qw - kh + 13) * 48;
    float s1 = 0.f, s2 = 0.f;
    #pragma unroll
    for (int c = 0; c < 48; ++c) { s1 += qf[c] * rp[c]; s2 += qf[c] * rpw[c]; }
    bh[kh] = s1; bw[kh] = s2;
  }
  // one pass: online softmax with deferred rescale
  float m = -1e30f, den = 0.f;
  float o[48] = {};
  for (int kh = 0; kh < 14; ++kh) {
    float bhh = bh[kh];
    int rowbase = (wh * 14 + kh) * 56 + wwn * 14;
    for (int kw2 = 0; kw2 < 14; ++kw2) {
      int kr = kh * 14 + kw2;
      const float4* krp = reinterpret_cast<const float4*>(kk[kr]);
      float s0 = 0.f, s1 = 0.f, s2 = 0.f, s3 = 0.f;
      #pragma unroll
      for (int c4 = 0; c4 < 12; c4 += 4) {
        float4 k0 = krp[c4], k1 = krp[c4 + 1], k2 = krp[c4 + 2], k3 = krp[c4 + 3];
        s0 += qf[c4*4+0]*k0.x + qf[c4*4+1]*k0.y + qf[c4*4+2]*k0.z + qf[c4*4+3]*k0.w;
        s1 += qf[c4*4+4]*k1.x + qf[c4*4+5]*k1.y + qf[c4*4+6]*k1.z + qf[c4*4+7]*k1.w;
        s2 += qf[c4*4+8]*k2.x + qf[c4*4+9]*k2.y + qf[c4*4+10]*k2.z + qf[c4*4+11]*k2.w;
        s3 += qf[c4*4+12]*k3.x + qf[c4*4+13]*k3.y + qf[c4*4+14]*k3.z + qf[c4*4+15]*k3.w;
      }
      float s = ((s0 + s1) + (s2 + s3)) * SCALEF + bhh + bw[kw2];
      if (s > m + 20.f) {                      // rare: deferred rescale
        float corr = expf(m - s);
        den *= corr;
        #pragma unroll
        for (int c = 0; c < 48; ++c) o[c] *= corr;
        m = s;
      }
      float p = expf(s - m);
      den += p;
      const ushort4* vp = reinterpret_cast<const ushort4*>(vwin + (size_t)(rowbase + kw2) * 48);
      #pragma unroll
      for (int c4 = 0; c4 < 12; ++c4) {
        ushort4 vv4 = vp[c4];
        o[c4*4+0] += p * b2f(vv4.x);
        o[c4*4+1] += p * b2f(vv4.y);
        o[c4*4+2] += p * b2f(vv4.z);
        o[c4*4+3] += p * b2f(vv4.w);
      }
    }
  }
  float rden = 1.f / den;
  int b = bnh >> 3, nh = bnh & 7;
  u16* op = obuf + ((size_t)(b * 56 + h) * 56 + w) * 384 + nh * 48;
  #pragma unroll
  for (int c = 0; c < 48; ++c) op[c] = f2b(o[c] * rden + qf[c]);   // + ori_q residual
}

extern "C" void kernel_launch(void* const* d_in, const int* in_sizes, int n_in,
                              void* d_out, int out_size, void* d_ws, size_t ws_size,
                              hipStream_t stream) {
  const float* x1      = (const float*)d_in[0];
  const float* x2      = (const float*)d_in[1];
  const float* norm1_w = (const float*)d_in[2];
  const float* norm1_b = (const float*)d_in[3];
  const float* qkv_w   = (const float*)d_in[4];
  const float* qkv_b   = (const float*)d_in[5];
  const float* poolq_w = (const float*)d_in[6];
  const float* poolk_w = (const float*)d_in[7];
  const float* poolv_w = (const float*)d_in[8];
  const float* nq_w    = (const float*)d_in[9];
  const float* nq_b    = (const float*)d_in[10];
  const float* nk_w    = (const float*)d_in[11];
  const float* nk_b    = (const float*)d_in[12];
  const float* nv_w    = (const float*)d_in[13];
  const float* nv_b    = (const float*)d_in[14];
  const float* rel_h   = (const float*)d_in[15];
  const float* rel_w   = (const float*)d_in[16];
  const float* proj_w  = (const float*)d_in[17];
  const float* proj_b  = (const float*)d_in[18];
  const float* norm2_w = (const float*)d_in[19];
  const float* norm2_b = (const float*)d_in[20];
  const float* fc1_w   = (const float*)d_in[21];
  const float* fc1_b   = (const float*)d_in[22];
  const float* fc2_w   = (const float*)d_in[23];
  const float* fc2_b   = (const float*)d_in[24];

  // ws overlay (u16 units). Peak = 57,802,752 u16 = 115.6 MB (same as round 2)
  u16* ws      = (u16*)d_ws;
  u16* qkv     = ws;                  // [0, 28901376)   qkv bf16, [3,64,3136,48]
  u16* xn      = ws + 28901376;       // [28901376, 38535168)   LN(x1) bf16
  u16* qkvc    = ws + 28901376;       // [28901376, 57802752)   post conv+LN (after xn dead)
  u16* obuf    = ws;                  // [0, 9633792)    attn out bf16 [B,H,W,384]
  u16* h1      = ws;                  // [0, 38535168)   gelu(fc1) bf16
  u16* yn      = ws + 48168960;       // [48168960, 57802752)   LN(y1) bf16
  u16* qkv_wt  = ws + 38535168;       // [38535168, 38977536)   bf16 [1152][384] (dies at step 3)
  u16* proj_wt = ws + 9633792;        // [9633792, 9781248)     bf16 [384][384]  (after qkv dead)
  u16* fc1_wt  = ws + 38535168;       // [38535168, 39124992)   bf16 [1536][384] (after qkvc dead)
  u16* fc2_wt  = ws + 39124992;       // [39124992, 39714816)   bf16 [384][1536]
  float* y1 = (float*)d_out;          // 9633792 f32
  float* y2 = y1 + 9633792;

  // 0a. convert qkv weights (transposed [N][K] bf16)
  wcvt_kernel<<<(384*1152 + 255)/256, 256, 0, stream>>>(qkv_w, qkv_wt, 384, 1152);
  // 1. xn = LN(x1)
  ln384_kernel<<<NTOK / 4, 256, 0, stream>>>(x1, norm1_w, norm1_b, xn);
  // 2. qkv = xn @ qkv_w + qkv_b  (MFMA, scattered layout)
  mgemm_kernel<0><<<dim3(196, 9), 256, 0, stream>>>(xn, qkv_wt, qkv_b, nullptr, qkv, NTOK, 1152, 384);
  // 3. q/k/v = LN(dwconv3x3(qkv))
  convln_kernel<<<3 * 64 * 3136 / 4, 256, 0, stream>>>(qkv, poolq_w, poolk_w, poolv_w,
                                                       nq_w, nq_b, nk_w, nk_b, nv_w, nv_b, qkvc);
  // 0b. convert proj weights (qkv region now dead)
  wcvt_kernel<<<(384*384 + 255)/256, 256, 0, stream>>>(proj_w, proj_wt, 384, 384);
  // 4. window attention (+ ori_q residual), permuted to [B,H,W,384]
  attn_kernel<<<1024, 256, 0, stream>>>(qkvc, rel_h, rel_w, obuf);
  // 0c. convert mlp weights (qkvc region now dead)
  wcvt_kernel<<<(384*1536 + 255)/256, 256, 0, stream>>>(fc1_w, fc1_wt, 384, 1536);
  wcvt_kernel<<<(1536*384 + 255)/256, 256, 0, stream>>>(fc2_w, fc2_wt, 1536, 384);
  // 5. y1 = x1 + obuf @ proj_w + proj_b
  mgemm_kernel<1><<<dim3(196, 3), 256, 0, stream>>>(obuf, proj_wt, proj_b, x1, y1, NTOK, 384, 384);
  // 6. yn = LN(y1)
  ln384_kernel<<<NTOK / 4, 256, 0, stream>>>(y1, norm2_w, norm2_b, yn);
  // 7. h1 = gelu(yn @ fc1_w + fc1_b)
  mgemm_kernel<2><<<dim3(196, 12), 256, 0, stream>>>(yn, fc1_wt, fc1_b, nullptr, h1, NTOK, 1536, 384);
  // 8. y2 = x2 + h1 @ fc2_w + fc2_b
  mgemm_kernel<1><<<dim3(196, 3), 256, 0, stream>>>(h1, fc2_wt, fc2_b, x2, y2, NTOK, 384, 1536);
}

// Round 4
// 664.283 us; speedup vs baseline: 2.9089x; 1.4284x over previous
//
#include <hip/hip_runtime.h>
#include <hip/hip_bf16.h>

typedef unsigned short u16;
typedef unsigned int u32;

#define DEVI __device__ __forceinline__

constexpr int BB = 8, HHc = 56, WWc = 56, DIMC = 384, NHC = 8, HDC = 48, WSZ = 14;
constexpr int NTOK = BB * HHc * WWc;          // 25088
constexpr int HIDC = 4 * DIMC;                // 1536
constexpr float EPSF = 1e-5f;
constexpr float SCALEF = 0.14433756729740643f;   // 48^-0.5

typedef short bf16x8 __attribute__((ext_vector_type(8)));
typedef float f32x4 __attribute__((ext_vector_type(4)));

// ---- bf16 helpers (raw ushort view) ----
DEVI float b2f(u16 u) { u32 x = ((u32)u) << 16; float f; __builtin_memcpy(&f, &x, 4); return f; }
DEVI u16 f2b(float f) {
  u32 x; __builtin_memcpy(&x, &f, 4);
  u32 r = (x >> 16) & 1u; x += 0x7fffu + r;
  return (u16)(x >> 16);
}

DEVI float wred_sum(float v) {
  #pragma unroll
  for (int o = 32; o; o >>= 1) v += __shfl_xor(v, o);
  return v;
}

// ---- weight convert f32 [K][N] -> bf16 [N][K] (transpose) ----
__global__ __launch_bounds__(256)
void wcvt_kernel(const float* __restrict__ in, u16* __restrict__ out, int K, int N) {
  int id = blockIdx.x * 256 + threadIdx.x;
  if (id >= K * N) return;
  int n = id / K, k = id - n * K;
  out[id] = f2b(in[(size_t)k * N + n]);
}

// ---- LayerNorm over 384: f32 in -> bf16 out (one wave per token) ----
__global__ __launch_bounds__(256)
void ln384_kernel(const float* __restrict__ x, const float* __restrict__ w,
                  const float* __restrict__ b, u16* __restrict__ out) {
  int wave = threadIdx.x >> 6, lane = threadIdx.x & 63;
  int tok = blockIdx.x * 4 + wave;
  if (tok >= NTOK) return;
  const float* xr = x + (size_t)tok * DIMC;
  float v[6]; float s = 0.f, ss = 0.f;
  #pragma unroll
  for (int i = 0; i < 6; ++i) {
    v[i] = xr[lane + i * 64];
    s += v[i]; ss += v[i] * v[i];
  }
  s = wred_sum(s); ss = wred_sum(ss);
  float mean = s * (1.f / 384.f);
  float var = ss * (1.f / 384.f) - mean * mean;
  float inv = rsqrtf(var + EPSF);
  u16* orow = out + (size_t)tok * DIMC;
  #pragma unroll
  for (int i = 0; i < 6; ++i) {
    int c = lane + i * 64;
    orow[c] = f2b((v[i] - mean) * inv * w[c] + b[c]);
  }
}

// ---- MFMA GEMM: C[M,N] = A(bf16)[M,K] @ Wt(bf16,[N][K])^T + bias ----
template<int MODE>
__global__ __launch_bounds__(256)
void mgemm_kernel(const u16* __restrict__ A, const u16* __restrict__ Wt,
                  const float* __restrict__ bias, const float* __restrict__ res,
                  void* __restrict__ outv, int M, int N, int K) {
  constexpr int LDT = 40;                       // padded k-stride (elements)
  __shared__ __attribute__((aligned(16))) u16 As[128 * LDT];
  __shared__ __attribute__((aligned(16))) u16 Bs[128 * LDT];
  int tid = threadIdx.x;
  int wave = tid >> 6, lane = tid & 63;
  int wr = wave >> 1, wc = wave & 1;
  int bm0 = blockIdx.x * 128, bn0 = blockIdx.y * 128;
  int srow = tid >> 1, shalf = tid & 1;         // staging: row, k-half(16 elems)
  const u16* ag = A  + (size_t)(bm0 + srow) * K + shalf * 16;
  const u16* bg = Wt + (size_t)(bn0 + srow) * K + shalf * 16;
  u16* asw = As + srow * LDT + shalf * 16;
  u16* bsw = Bs + srow * LDT + shalf * 16;
  int q = lane >> 4, r16 = lane & 15;
  const u16* ar = As + (wr * 64 + r16) * LDT + q * 8;
  const u16* br = Bs + (wc * 64 + r16) * LDT + q * 8;
  f32x4 acc[4][4] = {};
  for (int k0 = 0; k0 < K; k0 += 32) {
    uint4 av  = *reinterpret_cast<const uint4*>(ag + k0);
    uint4 av2 = *reinterpret_cast<const uint4*>(ag + k0 + 8);
    uint4 bv  = *reinterpret_cast<const uint4*>(bg + k0);
    uint4 bv2 = *reinterpret_cast<const uint4*>(bg + k0 + 8);
    __syncthreads();
    *reinterpret_cast<uint4*>(asw)     = av;
    *reinterpret_cast<uint4*>(asw + 8) = av2;
    *reinterpret_cast<uint4*>(bsw)     = bv;
    *reinterpret_cast<uint4*>(bsw + 8) = bv2;
    __syncthreads();
    bf16x8 af[4], bf[4];
    #pragma unroll
    for (int f = 0; f < 4; ++f) {
      af[f] = *reinterpret_cast<const bf16x8*>(ar + f * 16 * LDT);
      bf[f] = *reinterpret_cast<const bf16x8*>(br + f * 16 * LDT);
    }
    #pragma unroll
    for (int fm = 0; fm < 4; ++fm)
      #pragma unroll
      for (int fn = 0; fn < 4; ++fn)
        acc[fm][fn] = __builtin_amdgcn_mfma_f32_16x16x32_bf16(af[fm], bf[fn], acc[fm][fn], 0, 0, 0);
  }
  // epilogue: D layout col=lane&15, row=(lane>>4)*4+j
  int c0 = bn0 + wc * 64 + r16;
  int r0 = bm0 + wr * 64 + q * 4;
  #pragma unroll
  for (int fm = 0; fm < 4; ++fm) {
    #pragma unroll
    for (int fn = 0; fn < 4; ++fn) {
      int c = c0 + fn * 16;
      float bsv = bias[c];
      #pragma unroll
      for (int j = 0; j < 4; ++j) {
        int r = r0 + fm * 16 + j;
        float v = acc[fm][fn][j] + bsv;
        if constexpr (MODE == 0) {
          u16* out = (u16*)outv;
          int s = c / DIMC; int rem = c - s * DIMC;
          int nh = rem / HDC; int ch = rem - nh * HDC;
          int b = r / 3136; int hw = r - b * 3136;
          out[(((size_t)(s * 64 + b * 8 + nh)) * 3136 + hw) * 48 + ch] = f2b(v);
        } else if constexpr (MODE == 1) {
          float* out = (float*)outv;
          size_t idx = (size_t)r * N + c;
          out[idx] = v + res[idx];
        } else {
          u16* out = (u16*)outv;
          size_t idx = (size_t)r * N + c;
          out[idx] = f2b(0.5f * v * (1.0f + erff(v * 0.70710678118654752440f)));
        }
      }
    }
  }
}

// ---- depthwise 3x3 conv (pad 1) + LayerNorm over 48 channels ----
__global__ __launch_bounds__(256)
void convln_kernel(const u16* __restrict__ qkv,
                   const float* __restrict__ wq, const float* __restrict__ wk, const float* __restrict__ wv,
                   const float* __restrict__ gq, const float* __restrict__ bq,
                   const float* __restrict__ gk, const float* __restrict__ bk,
                   const float* __restrict__ gv, const float* __restrict__ bv,
                   u16* __restrict__ out) {
  int wave = threadIdx.x >> 6, lane = threadIdx.x & 63;
  int pix = blockIdx.x * 4 + wave;          // [0, 3*64*3136)
  int sb = pix / 3136;                      // s*64 + bnh
  int hw = pix - sb * 3136;
  int s = sb >> 6;
  int h = hw / 56, w = hw - h * 56;
  const float* wgt = (s == 0) ? wq : ((s == 1) ? wk : wv);
  const float* gam = (s == 0) ? gq : ((s == 1) ? gk : gv);
  const float* bet = (s == 0) ? bq : ((s == 1) ? bk : bv);
  float acc = 0.f;
  int c = lane;
  if (c < 48) {
    const u16* base = qkv + (size_t)sb * 3136 * 48;
    #pragma unroll
    for (int dy = -1; dy <= 1; ++dy) {
      int hh = h + dy;
      if (hh < 0 || hh >= 56) continue;
      #pragma unroll
      for (int dx = -1; dx <= 1; ++dx) {
        int ww = w + dx;
        if (ww < 0 || ww >= 56) continue;
        acc += b2f(base[(size_t)(hh * 56 + ww) * 48 + c]) *
               wgt[((dy + 1) * 3 + (dx + 1)) * 48 + c];
      }
    }
  }
  float sv = (c < 48) ? acc : 0.f;
  float sum = wred_sum(sv);
  float ssq = wred_sum(sv * sv);
  float mean = sum * (1.f / 48.f);
  float var = ssq * (1.f / 48.f) - mean * mean;
  float inv = rsqrtf(var + EPSF);
  if (c < 48)
    out[(size_t)pix * 48 + c] = f2b((acc - mean) * inv * gam[c] + bet[c]);
}

// ---- MFMA window attention: one block (4 waves) per window, 1024 windows ----
// LDS: Q[208][72] (unscaled), K[208][72] (pre-scaled), V^T[48][232],
//      QRW[208][56] (bias tables bh|bw), PB = Rel staging / per-wave P tiles.
#define MFMA16(a, b, c) __builtin_amdgcn_mfma_f32_16x16x32_bf16((a), (b), (c), 0, 0, 0)
__global__ __launch_bounds__(256)
void attn_kernel(const u16* __restrict__ qkvc, const float* __restrict__ rel_h,
                 const float* __restrict__ rel_w, u16* __restrict__ obuf) {
  __shared__ __attribute__((aligned(16))) u16 QL[208 * 72];
  __shared__ __attribute__((aligned(16))) u16 KL[208 * 72];
  __shared__ __attribute__((aligned(16))) u16 VT[48 * 232];
  __shared__ __attribute__((aligned(16))) u16 QRW[208 * 56];
  __shared__ __attribute__((aligned(16))) u16 PB[4 * 16 * 232];

  int wid = blockIdx.x;
  int bnh = wid >> 4, wrem = wid & 15, wh = wrem >> 2, wwn = wrem & 3;
  int tid = threadIdx.x;
  int wave = tid >> 6, lane = tid & 63;
  int q4 = lane >> 4, r16 = lane & 15;

  // ---- zero pads (everything; staging overwrites live parts) ----
  { u32* z;
    z = (u32*)QL; for (int i = tid; i < 208 * 72 / 2; i += 256) z[i] = 0;
    z = (u32*)KL; for (int i = tid; i < 208 * 72 / 2; i += 256) z[i] = 0;
    z = (u32*)VT; for (int i = tid; i < 48 * 232 / 2; i += 256) z[i] = 0;
    z = (u32*)PB; for (int i = tid; i < 4 * 16 * 232 / 2; i += 256) z[i] = 0;
  }
  __syncthreads();
  // ---- stage Q, K (scaled), V^T, Rel ----
  size_t qbase = (size_t)bnh * 3136 * 48;
  size_t kbase = ((size_t)(64 + bnh) * 3136) * 48;
  size_t vbase = ((size_t)(128 + bnh) * 3136) * 48;
  for (int i = tid; i < 196 * 12; i += 256) {
    int r = i / 12, c4 = (i - r * 12) * 4;
    int h = wh * 14 + r / 14, w = wwn * 14 + r % 14;
    size_t g = (size_t)(h * 56 + w) * 48 + c4;
    ushort4 qv = *reinterpret_cast<const ushort4*>(qkvc + qbase + g);
    *reinterpret_cast<ushort4*>(QL + r * 72 + c4) = qv;
    ushort4 kv = *reinterpret_cast<const ushort4*>(qkvc + kbase + g);
    kv.x = f2b(b2f(kv.x) * SCALEF); kv.y = f2b(b2f(kv.y) * SCALEF);
    kv.z = f2b(b2f(kv.z) * SCALEF); kv.w = f2b(b2f(kv.w) * SCALEF);
    *reinterpret_cast<ushort4*>(KL + r * 72 + c4) = kv;
    ushort4 vv = *reinterpret_cast<const ushort4*>(qkvc + vbase + g);
    VT[(c4 + 0) * 232 + r] = vv.x; VT[(c4 + 1) * 232 + r] = vv.y;
    VT[(c4 + 2) * 232 + r] = vv.z; VT[(c4 + 3) * 232 + r] = vv.w;
  }
  for (int i = tid; i < 54 * 48; i += 256) {
    int r = i / 48, c = i - r * 48;
    float v = (r < 27) ? rel_h[r * 48 + c] : rel_w[(r - 27) * 48 + c];
    PB[r * 72 + c] = f2b(v);            // Rel rows 0..26 = Rh, 27..53 = Rw
  }
  __syncthreads();
  // ---- QRW = Q @ Rel^T (bias tables; rows=q, cols 0..26 bh-idx, 27..53 bw-idx) ----
  for (int mf = wave; mf < 13; mf += 4) {
    bf16x8 af0 = *reinterpret_cast<const bf16x8*>(QL + (mf * 16 + r16) * 72 + q4 * 8);
    bf16x8 af1 = *reinterpret_cast<const bf16x8*>(QL + (mf * 16 + r16) * 72 + 32 + q4 * 8);
    #pragma unroll
    for (int nf = 0; nf < 4; ++nf) {
      bf16x8 b0 = *reinterpret_cast<const bf16x8*>(PB + (nf * 16 + r16) * 72 + q4 * 8);
      bf16x8 b1 = *reinterpret_cast<const bf16x8*>(PB + (nf * 16 + r16) * 72 + 32 + q4 * 8);
      f32x4 acc = {};
      acc = MFMA16(af0, b0, acc);
      acc = MFMA16(af1, b1, acc);
      int col = nf * 16 + r16;
      if (col < 54) {
        #pragma unroll
        for (int j = 0; j < 4; ++j)
          QRW[(mf * 16 + q4 * 4 + j) * 56 + col] = f2b(acc[j]);
      }
    }
  }
  __syncthreads();
  // ---- zero this wave's P-tile tail cols (208..231) ----
  u16* Pw = PB + wave * 16 * 232;
  for (int i = lane; i < 16 * 24; i += 64) {
    int r = i / 24;
    Pw[r * 232 + 208 + (i - r * 24)] = 0;
  }
  // per-lane key constants
  int khs[13], kws[13];
  #pragma unroll
  for (int nf = 0; nf < 13; ++nf) {
    int key = nf * 16 + r16;
    khs[nf] = key / 14;
    kws[nf] = key - khs[nf] * 14;
  }
  int bI = bnh >> 3, nhI = bnh & 7;
  // ---- main loop over this wave's query fragments ----
  for (int mf = wave; mf < 13; mf += 4) {
    bf16x8 af0 = *reinterpret_cast<const bf16x8*>(QL + (mf * 16 + r16) * 72 + q4 * 8);
    bf16x8 af1 = *reinterpret_cast<const bf16x8*>(QL + (mf * 16 + r16) * 72 + 32 + q4 * 8);
    f32x4 s[13];
    #pragma unroll
    for (int nf = 0; nf < 13; ++nf) {
      bf16x8 b0 = *reinterpret_cast<const bf16x8*>(KL + (nf * 16 + r16) * 72 + q4 * 8);
      bf16x8 b1 = *reinterpret_cast<const bf16x8*>(KL + (nf * 16 + r16) * 72 + 32 + q4 * 8);
      f32x4 a = {};
      a = MFMA16(af0, b0, a);
      a = MFMA16(af1, b1, a);
      s[nf] = a;
    }
    int rowb = mf * 16 + q4 * 4;
    // bias + mask
    #pragma unroll
    for (int j = 0; j < 4; ++j) {
      int row = rowb + j;
      int qh = row / 14, qw = row - qh * 14;
      const u16* qr = QRW + row * 56;
      #pragma unroll
      for (int nf = 0; nf < 13; ++nf) {
        int ih = qh - khs[nf] + 13; ih = (ih < 0) ? 0 : ih;
        int iw = 27 + qw - kws[nf] + 13;
        float sv = s[nf][j] + b2f(qr[ih]) + b2f(qr[iw]);
        s[nf][j] = (nf * 16 + r16 < 196) ? sv : -1e30f;
      }
    }
    // row max + exp + den + P store
    float mrow[4], den[4];
    #pragma unroll
    for (int j = 0; j < 4; ++j) {
      float mm = s[0][j];
      #pragma unroll
      for (int nf = 1; nf < 13; ++nf) mm = fmaxf(mm, s[nf][j]);
      #pragma unroll
      for (int off = 1; off < 16; off <<= 1) mm = fmaxf(mm, __shfl_xor(mm, off));
      mrow[j] = mm; den[j] = 0.f;
    }
    #pragma unroll
    for (int nf = 0; nf < 13; ++nf) {
      #pragma unroll
      for (int j = 0; j < 4; ++j) {
        float p = __expf(s[nf][j] - mrow[j]);
        den[j] += p;
        Pw[(q4 * 4 + j) * 232 + nf * 16 + r16] = f2b(p);
      }
    }
    #pragma unroll
    for (int j = 0; j < 4; ++j)
      #pragma unroll
      for (int off = 1; off < 16; off <<= 1) den[j] += __shfl_xor(den[j], off);
    // PV: O = P @ V^T  (k = 224, zero-padded)
    f32x4 o[3] = {};
    #pragma unroll
    for (int ks = 0; ks < 7; ++ks) {
      bf16x8 ap = *reinterpret_cast<const bf16x8*>(Pw + r16 * 232 + ks * 32 + q4 * 8);
      #pragma unroll
      for (int nf3 = 0; nf3 < 3; ++nf3) {
        bf16x8 bv = *reinterpret_cast<const bf16x8*>(VT + (nf3 * 16 + r16) * 232 + ks * 32 + q4 * 8);
        o[nf3] = MFMA16(ap, bv, o[nf3]);
      }
    }
    // epilogue: o/den + q residual -> obuf [B,H,W,384]
    #pragma unroll
    for (int j = 0; j < 4; ++j) {
      int row = rowb + j;
      if (row < 196) {
        float rden = 1.f / den[j];
        int rh = row / 14;
        int h = wh * 14 + rh, w = wwn * 14 + row - rh * 14;
        u16* op = obuf + ((size_t)(bI * 56 + h) * 56 + w) * 384 + nhI * 48;
        #pragma unroll
        for (int nf3 = 0; nf3 < 3; ++nf3) {
          int col = nf3 * 16 + r16;
          op[col] = f2b(o[nf3][j] * rden + b2f(QL[row * 72 + col]));
        }
      }
    }
  }
}

extern "C" void kernel_launch(void* const* d_in, const int* in_sizes, int n_in,
                              void* d_out, int out_size, void* d_ws, size_t ws_size,
                              hipStream_t stream) {
  const float* x1      = (const float*)d_in[0];
  const float* x2      = (const float*)d_in[1];
  const float* norm1_w = (const float*)d_in[2];
  const float* norm1_b = (const float*)d_in[3];
  const float* qkv_w   = (const float*)d_in[4];
  const float* qkv_b   = (const float*)d_in[5];
  const float* poolq_w = (const float*)d_in[6];
  const float* poolk_w = (const float*)d_in[7];
  const float* poolv_w = (const float*)d_in[8];
  const float* nq_w    = (const float*)d_in[9];
  const float* nq_b    = (const float*)d_in[10];
  const float* nk_w    = (const float*)d_in[11];
  const float* nk_b    = (const float*)d_in[12];
  const float* nv_w    = (const float*)d_in[13];
  const float* nv_b    = (const float*)d_in[14];
  const float* rel_h   = (const float*)d_in[15];
  const float* rel_w   = (const float*)d_in[16];
  const float* proj_w  = (const float*)d_in[17];
  const float* proj_b  = (const float*)d_in[18];
  const float* norm2_w = (const float*)d_in[19];
  const float* norm2_b = (const float*)d_in[20];
  const float* fc1_w   = (const float*)d_in[21];
  const float* fc1_b   = (const float*)d_in[22];
  const float* fc2_w   = (const float*)d_in[23];
  const float* fc2_b   = (const float*)d_in[24];

  // ws overlay (u16 units). Peak = 57,802,752 u16 = 115.6 MB
  u16* ws      = (u16*)d_ws;
  u16* qkv     = ws;                  // [0, 28901376)   qkv bf16, [3,64,3136,48]
  u16* xn      = ws + 28901376;       // LN(x1) bf16
  u16* qkvc    = ws + 28901376;       // post conv+LN (after xn dead)
  u16* obuf    = ws;                  // attn out bf16 [B,H,W,384]
  u16* h1      = ws;                  // gelu(fc1) bf16
  u16* yn      = ws + 48168960;       // LN(y1) bf16
  u16* qkv_wt  = ws + 38535168;       // bf16 [1152][384] (dies at step 3)
  u16* proj_wt = ws + 9633792;        // bf16 [384][384]  (after qkv dead)
  u16* fc1_wt  = ws + 38535168;       // bf16 [1536][384] (after qkvc dead)
  u16* fc2_wt  = ws + 39124992;       // bf16 [384][1536]
  float* y1 = (float*)d_out;          // 9633792 f32
  float* y2 = y1 + 9633792;

  // 0a. convert qkv weights (transposed [N][K] bf16)
  wcvt_kernel<<<(384*1152 + 255)/256, 256, 0, stream>>>(qkv_w, qkv_wt, 384, 1152);
  // 1. xn = LN(x1)
  ln384_kernel<<<NTOK / 4, 256, 0, stream>>>(x1, norm1_w, norm1_b, xn);
  // 2. qkv = xn @ qkv_w + qkv_b  (MFMA, scattered layout)
  mgemm_kernel<0><<<dim3(196, 9), 256, 0, stream>>>(xn, qkv_wt, qkv_b, nullptr, qkv, NTOK, 1152, 384);
  // 3. q/k/v = LN(dwconv3x3(qkv))
  convln_kernel<<<3 * 64 * 3136 / 4, 256, 0, stream>>>(qkv, poolq_w, poolk_w, poolv_w,
                                                       nq_w, nq_b, nk_w, nk_b, nv_w, nv_b, qkvc);
  // 0b. convert proj weights (qkv region now dead)
  wcvt_kernel<<<(384*384 + 255)/256, 256, 0, stream>>>(proj_w, proj_wt, 384, 384);
  // 4. MFMA window attention (+ ori_q residual), permuted to [B,H,W,384]
  attn_kernel<<<1024, 256, 0, stream>>>(qkvc, rel_h, rel_w, obuf);
  // 0c. convert mlp weights (qkvc region now dead)
  wcvt_kernel<<<(384*1536 + 255)/256, 256, 0, stream>>>(fc1_w, fc1_wt, 384, 1536);
  wcvt_kernel<<<(1536*384 + 255)/256, 256, 0, stream>>>(fc2_w, fc2_wt, 1536, 384);
  // 5. y1 = x1 + obuf @ proj_w + proj_b
  mgemm_kernel<1><<<dim3(196, 3), 256, 0, stream>>>(obuf, proj_wt, proj_b, x1, y1, NTOK, 384, 384);
  // 6. yn = LN(y1)
  ln384_kernel<<<NTOK / 4, 256, 0, stream>>>(y1, norm2_w, norm2_b, yn);
  // 7. h1 = gelu(yn @ fc1_w + fc1_b)
  mgemm_kernel<2><<<dim3(196, 12), 256, 0, stream>>>(yn, fc1_wt, fc1_b, nullptr, h1, NTOK, 1536, 384);
  // 8. y2 = x2 + h1 @ fc2_w + fc2_b
  mgemm_kernel<1><<<dim3(196, 3), 256, 0, stream>>>(h1, fc2_wt, fc2_b, x2, y2, NTOK, 384, 1536);
}

// Round 5
// 452.014 us; speedup vs baseline: 4.2750x; 1.4696x over previous
//
#include <hip/hip_runtime.h>
#include <hip/hip_bf16.h>

typedef unsigned short u16;
typedef unsigned int u32;

#define DEVI __device__ __forceinline__

constexpr int BB = 8, HHc = 56, WWc = 56, DIMC = 384, NHC = 8, HDC = 48, WSZ = 14;
constexpr int NTOK = BB * HHc * WWc;          // 25088
constexpr int HIDC = 4 * DIMC;                // 1536
constexpr float EPSF = 1e-5f;
constexpr float SCALEF = 0.14433756729740643f;   // 48^-0.5

typedef short bf16x8 __attribute__((ext_vector_type(8)));
typedef float f32x4 __attribute__((ext_vector_type(4)));

// ---- bf16 helpers (raw ushort view) ----
DEVI float b2f(u16 u) { u32 x = ((u32)u) << 16; float f; __builtin_memcpy(&f, &x, 4); return f; }
DEVI float uasf(u32 x) { float f; __builtin_memcpy(&f, &x, 4); return f; }
DEVI u16 f2b(float f) {
  u32 x; __builtin_memcpy(&x, &f, 4);
  u32 r = (x >> 16) & 1u; x += 0x7fffu + r;
  return (u16)(x >> 16);
}

DEVI float wred_sum(float v) {
  #pragma unroll
  for (int o = 32; o; o >>= 1) v += __shfl_xor(v, o);
  return v;
}

// ---- weight convert f32 [K][N] -> bf16 [N][K] (transpose) ----
__global__ __launch_bounds__(256)
void wcvt_kernel(const float* __restrict__ in, u16* __restrict__ out, int K, int N) {
  int id = blockIdx.x * 256 + threadIdx.x;
  if (id >= K * N) return;
  int n = id / K, k = id - n * K;
  out[id] = f2b(in[(size_t)k * N + n]);
}

// ---- LayerNorm over 384: f32 in -> bf16 out (one wave per token) ----
__global__ __launch_bounds__(256)
void ln384_kernel(const float* __restrict__ x, const float* __restrict__ w,
                  const float* __restrict__ b, u16* __restrict__ out) {
  int wave = threadIdx.x >> 6, lane = threadIdx.x & 63;
  int tok = blockIdx.x * 4 + wave;
  if (tok >= NTOK) return;
  const float* xr = x + (size_t)tok * DIMC;
  float v[6]; float s = 0.f, ss = 0.f;
  #pragma unroll
  for (int i = 0; i < 6; ++i) {
    v[i] = xr[lane + i * 64];
    s += v[i]; ss += v[i] * v[i];
  }
  s = wred_sum(s); ss = wred_sum(ss);
  float mean = s * (1.f / 384.f);
  float var = ss * (1.f / 384.f) - mean * mean;
  float inv = rsqrtf(var + EPSF);
  u16* orow = out + (size_t)tok * DIMC;
  #pragma unroll
  for (int i = 0; i < 6; ++i) {
    int c = lane + i * 64;
    orow[c] = f2b((v[i] - mean) * inv * w[c] + b[c]);
  }
}

// ---- MFMA GEMM: C[M,N] = A(bf16)[M,K] @ Wt(bf16,[N][K])^T + bias ----
template<int MODE>
__global__ __launch_bounds__(256)
void mgemm_kernel(const u16* __restrict__ A, const u16* __restrict__ Wt,
                  const float* __restrict__ bias, const float* __restrict__ res,
                  void* __restrict__ outv, int M, int N, int K) {
  constexpr int LDT = 40;                       // padded k-stride (elements)
  __shared__ __attribute__((aligned(16))) u16 As[128 * LDT];
  __shared__ __attribute__((aligned(16))) u16 Bs[128 * LDT];
  int tid = threadIdx.x;
  int wave = tid >> 6, lane = tid & 63;
  int wr = wave >> 1, wc = wave & 1;
  int bm0 = blockIdx.x * 128, bn0 = blockIdx.y * 128;
  int srow = tid >> 1, shalf = tid & 1;         // staging: row, k-half(16 elems)
  const u16* ag = A  + (size_t)(bm0 + srow) * K + shalf * 16;
  const u16* bg = Wt + (size_t)(bn0 + srow) * K + shalf * 16;
  u16* asw = As + srow * LDT + shalf * 16;
  u16* bsw = Bs + srow * LDT + shalf * 16;
  int q = lane >> 4, r16 = lane & 15;
  const u16* ar = As + (wr * 64 + r16) * LDT + q * 8;
  const u16* br = Bs + (wc * 64 + r16) * LDT + q * 8;
  f32x4 acc[4][4] = {};
  for (int k0 = 0; k0 < K; k0 += 32) {
    uint4 av  = *reinterpret_cast<const uint4*>(ag + k0);
    uint4 av2 = *reinterpret_cast<const uint4*>(ag + k0 + 8);
    uint4 bv  = *reinterpret_cast<const uint4*>(bg + k0);
    uint4 bv2 = *reinterpret_cast<const uint4*>(bg + k0 + 8);
    __syncthreads();
    *reinterpret_cast<uint4*>(asw)     = av;
    *reinterpret_cast<uint4*>(asw + 8) = av2;
    *reinterpret_cast<uint4*>(bsw)     = bv;
    *reinterpret_cast<uint4*>(bsw + 8) = bv2;
    __syncthreads();
    bf16x8 af[4], bf[4];
    #pragma unroll
    for (int f = 0; f < 4; ++f) {
      af[f] = *reinterpret_cast<const bf16x8*>(ar + f * 16 * LDT);
      bf[f] = *reinterpret_cast<const bf16x8*>(br + f * 16 * LDT);
    }
    #pragma unroll
    for (int fm = 0; fm < 4; ++fm)
      #pragma unroll
      for (int fn = 0; fn < 4; ++fn)
        acc[fm][fn] = __builtin_amdgcn_mfma_f32_16x16x32_bf16(af[fm], bf[fn], acc[fm][fn], 0, 0, 0);
  }
  // epilogue: D layout col=lane&15, row=(lane>>4)*4+j
  int c0 = bn0 + wc * 64 + r16;
  int r0 = bm0 + wr * 64 + q * 4;
  #pragma unroll
  for (int fm = 0; fm < 4; ++fm) {
    #pragma unroll
    for (int fn = 0; fn < 4; ++fn) {
      int c = c0 + fn * 16;
      float bsv = bias[c];
      #pragma unroll
      for (int j = 0; j < 4; ++j) {
        int r = r0 + fm * 16 + j;
        float v = acc[fm][fn][j] + bsv;
        if constexpr (MODE == 0) {
          u16* out = (u16*)outv;
          int s = c / DIMC; int rem = c - s * DIMC;
          int nh = rem / HDC; int ch = rem - nh * HDC;
          int b = r / 3136; int hw = r - b * 3136;
          out[(((size_t)(s * 64 + b * 8 + nh)) * 3136 + hw) * 48 + ch] = f2b(v);
        } else if constexpr (MODE == 1) {
          float* out = (float*)outv;
          size_t idx = (size_t)r * N + c;
          out[idx] = v + res[idx];
        } else {
          u16* out = (u16*)outv;
          size_t idx = (size_t)r * N + c;
          out[idx] = f2b(0.5f * v * (1.0f + erff(v * 0.70710678118654752440f)));
        }
      }
    }
  }
}

// ---- depthwise 3x3 conv (pad 1) + LayerNorm over 48 channels ----
// thread-per-pixel: vectorized loads, in-register LN, LDS-staged weights
__global__ __launch_bounds__(256)
void convln_kernel(const u16* __restrict__ qkv,
                   const float* __restrict__ wq, const float* __restrict__ wk, const float* __restrict__ wv,
                   const float* __restrict__ gq, const float* __restrict__ bq,
                   const float* __restrict__ gk, const float* __restrict__ bk,
                   const float* __restrict__ gv, const float* __restrict__ bv,
                   u16* __restrict__ out) {
  __shared__ __attribute__((aligned(16))) float wsm[432];
  __shared__ __attribute__((aligned(16))) float gsm[48];
  __shared__ __attribute__((aligned(16))) float bsm[48];
  int tid = threadIdx.x;
  int sb = blockIdx.y;                  // 0..191 = s*64 + bnh
  int s = sb >> 6;
  const float* wgt = (s == 0) ? wq : ((s == 1) ? wk : wv);
  const float* gam = (s == 0) ? gq : ((s == 1) ? gk : gv);
  const float* bet = (s == 0) ? bq : ((s == 1) ? bk : bv);
  for (int i = tid; i < 432; i += 256) wsm[i] = wgt[i];
  if (tid < 48) { gsm[tid] = gam[tid]; bsm[tid] = bet[tid]; }
  __syncthreads();
  int hw = blockIdx.x * 256 + tid;
  if (hw >= 3136) return;
  int h = hw / 56, w = hw - h * 56;
  const u16* img = qkv + (size_t)sb * (3136 * 48);
  float acc[48];
  #pragma unroll
  for (int c = 0; c < 48; ++c) acc[c] = 0.f;
  #pragma unroll
  for (int dy = -1; dy <= 1; ++dy) {
    int hh = h + dy;
    if ((unsigned)hh >= 56u) continue;
    #pragma unroll
    for (int dx = -1; dx <= 1; ++dx) {
      int ww = w + dx;
      if ((unsigned)ww >= 56u) continue;
      const uint4* p = reinterpret_cast<const uint4*>(img + (size_t)(hh * 56 + ww) * 48);
      const float4* wr = reinterpret_cast<const float4*>(wsm + ((dy + 1) * 3 + (dx + 1)) * 48);
      #pragma unroll
      for (int g = 0; g < 6; ++g) {
        uint4 v = p[g];
        float4 w0 = wr[g * 2], w1 = wr[g * 2 + 1];
        acc[g * 8 + 0] += uasf(v.x << 16)          * w0.x;
        acc[g * 8 + 1] += uasf(v.x & 0xFFFF0000u)  * w0.y;
        acc[g * 8 + 2] += uasf(v.y << 16)          * w0.z;
        acc[g * 8 + 3] += uasf(v.y & 0xFFFF0000u)  * w0.w;
        acc[g * 8 + 4] += uasf(v.z << 16)          * w1.x;
        acc[g * 8 + 5] += uasf(v.z & 0xFFFF0000u)  * w1.y;
        acc[g * 8 + 6] += uasf(v.w << 16)          * w1.z;
        acc[g * 8 + 7] += uasf(v.w & 0xFFFF0000u)  * w1.w;
      }
    }
  }
  float sum = 0.f, ssq = 0.f;
  #pragma unroll
  for (int c = 0; c < 48; ++c) { sum += acc[c]; ssq += acc[c] * acc[c]; }
  float mean = sum * (1.f / 48.f);
  float var = ssq * (1.f / 48.f) - mean * mean;
  float inv = rsqrtf(var + EPSF);
  u16* op = out + ((size_t)sb * 3136 + hw) * 48;
  #pragma unroll
  for (int g = 0; g < 6; ++g) {
    const float4 gm0 = *reinterpret_cast<const float4*>(gsm + g * 8);
    const float4 gm1 = *reinterpret_cast<const float4*>(gsm + g * 8 + 4);
    const float4 bt0 = *reinterpret_cast<const float4*>(bsm + g * 8);
    const float4 bt1 = *reinterpret_cast<const float4*>(bsm + g * 8 + 4);
    uint4 ov;
    u32 a0 = f2b((acc[g * 8 + 0] - mean) * inv * gm0.x + bt0.x);
    u32 a1 = f2b((acc[g * 8 + 1] - mean) * inv * gm0.y + bt0.y);
    u32 a2 = f2b((acc[g * 8 + 2] - mean) * inv * gm0.z + bt0.z);
    u32 a3 = f2b((acc[g * 8 + 3] - mean) * inv * gm0.w + bt0.w);
    u32 a4 = f2b((acc[g * 8 + 4] - mean) * inv * gm1.x + bt1.x);
    u32 a5 = f2b((acc[g * 8 + 5] - mean) * inv * gm1.y + bt1.y);
    u32 a6 = f2b((acc[g * 8 + 6] - mean) * inv * gm1.z + bt1.z);
    u32 a7 = f2b((acc[g * 8 + 7] - mean) * inv * gm1.w + bt1.w);
    ov.x = a0 | (a1 << 16);
    ov.y = a2 | (a3 << 16);
    ov.z = a4 | (a5 << 16);
    ov.w = a6 | (a7 << 16);
    *reinterpret_cast<uint4*>(op + g * 8) = ov;
  }
}

// ---- MFMA window attention: one block (4 waves) per window, 1024 windows ----
#define MFMA16(a, b, c) __builtin_amdgcn_mfma_f32_16x16x32_bf16((a), (b), (c), 0, 0, 0)
__global__ __launch_bounds__(256)
void attn_kernel(const u16* __restrict__ qkvc, const float* __restrict__ rel_h,
                 const float* __restrict__ rel_w, u16* __restrict__ obuf) {
  __shared__ __attribute__((aligned(16))) u16 QL[208 * 72];
  __shared__ __attribute__((aligned(16))) u16 KL[208 * 72];
  __shared__ __attribute__((aligned(16))) u16 VT[48 * 232];
  __shared__ __attribute__((aligned(16))) u16 QRW[208 * 56];
  __shared__ __attribute__((aligned(16))) u16 PB[4 * 16 * 232];

  int wid = blockIdx.x;
  int bnh = wid >> 4, wrem = wid & 15, wh = wrem >> 2, wwn = wrem & 3;
  int tid = threadIdx.x;
  int wave = tid >> 6, lane = tid & 63;
  int q4 = lane >> 4, r16 = lane & 15;

  { u32* z;
    z = (u32*)QL; for (int i = tid; i < 208 * 72 / 2; i += 256) z[i] = 0;
    z = (u32*)KL; for (int i = tid; i < 208 * 72 / 2; i += 256) z[i] = 0;
    z = (u32*)VT; for (int i = tid; i < 48 * 232 / 2; i += 256) z[i] = 0;
    z = (u32*)PB; for (int i = tid; i < 4 * 16 * 232 / 2; i += 256) z[i] = 0;
  }
  __syncthreads();
  size_t qbase = (size_t)bnh * 3136 * 48;
  size_t kbase = ((size_t)(64 + bnh) * 3136) * 48;
  size_t vbase = ((size_t)(128 + bnh) * 3136) * 48;
  for (int i = tid; i < 196 * 12; i += 256) {
    int r = i / 12, c4 = (i - r * 12) * 4;
    int h = wh * 14 + r / 14, w = wwn * 14 + r % 14;
    size_t g = (size_t)(h * 56 + w) * 48 + c4;
    ushort4 qv = *reinterpret_cast<const ushort4*>(qkvc + qbase + g);
    *reinterpret_cast<ushort4*>(QL + r * 72 + c4) = qv;
    ushort4 kv = *reinterpret_cast<const ushort4*>(qkvc + kbase + g);
    kv.x = f2b(b2f(kv.x) * SCALEF); kv.y = f2b(b2f(kv.y) * SCALEF);
    kv.z = f2b(b2f(kv.z) * SCALEF); kv.w = f2b(b2f(kv.w) * SCALEF);
    *reinterpret_cast<ushort4*>(KL + r * 72 + c4) = kv;
    ushort4 vv = *reinterpret_cast<const ushort4*>(qkvc + vbase + g);
    VT[(c4 + 0) * 232 + r] = vv.x; VT[(c4 + 1) * 232 + r] = vv.y;
    VT[(c4 + 2) * 232 + r] = vv.z; VT[(c4 + 3) * 232 + r] = vv.w;
  }
  for (int i = tid; i < 54 * 48; i += 256) {
    int r = i / 48, c = i - r * 48;
    float v = (r < 27) ? rel_h[r * 48 + c] : rel_w[(r - 27) * 48 + c];
    PB[r * 72 + c] = f2b(v);            // Rel rows 0..26 = Rh, 27..53 = Rw
  }
  __syncthreads();
  // QRW = Q @ Rel^T
  for (int mf = wave; mf < 13; mf += 4) {
    bf16x8 af0 = *reinterpret_cast<const bf16x8*>(QL + (mf * 16 + r16) * 72 + q4 * 8);
    bf16x8 af1 = *reinterpret_cast<const bf16x8*>(QL + (mf * 16 + r16) * 72 + 32 + q4 * 8);
    #pragma unroll
    for (int nf = 0; nf < 4; ++nf) {
      bf16x8 b0 = *reinterpret_cast<const bf16x8*>(PB + (nf * 16 + r16) * 72 + q4 * 8);
      bf16x8 b1 = *reinterpret_cast<const bf16x8*>(PB + (nf * 16 + r16) * 72 + 32 + q4 * 8);
      f32x4 acc = {};
      acc = MFMA16(af0, b0, acc);
      acc = MFMA16(af1, b1, acc);
      int col = nf * 16 + r16;
      if (col < 54) {
        #pragma unroll
        for (int j = 0; j < 4; ++j)
          QRW[(mf * 16 + q4 * 4 + j) * 56 + col] = f2b(acc[j]);
      }
    }
  }
  __syncthreads();
  u16* Pw = PB + wave * 16 * 232;
  for (int i = lane; i < 16 * 24; i += 64) {
    int r = i / 24;
    Pw[r * 232 + 208 + (i - r * 24)] = 0;
  }
  int khs[13], kws[13];
  #pragma unroll
  for (int nf = 0; nf < 13; ++nf) {
    int key = nf * 16 + r16;
    khs[nf] = key / 14;
    kws[nf] = key - khs[nf] * 14;
  }
  int bI = bnh >> 3, nhI = bnh & 7;
  for (int mf = wave; mf < 13; mf += 4) {
    bf16x8 af0 = *reinterpret_cast<const bf16x8*>(QL + (mf * 16 + r16) * 72 + q4 * 8);
    bf16x8 af1 = *reinterpret_cast<const bf16x8*>(QL + (mf * 16 + r16) * 72 + 32 + q4 * 8);
    f32x4 s[13];
    #pragma unroll
    for (int nf = 0; nf < 13; ++nf) {
      bf16x8 b0 = *reinterpret_cast<const bf16x8*>(KL + (nf * 16 + r16) * 72 + q4 * 8);
      bf16x8 b1 = *reinterpret_cast<const bf16x8*>(KL + (nf * 16 + r16) * 72 + 32 + q4 * 8);
      f32x4 a = {};
      a = MFMA16(af0, b0, a);
      a = MFMA16(af1, b1, a);
      s[nf] = a;
    }
    int rowb = mf * 16 + q4 * 4;
    #pragma unroll
    for (int j = 0; j < 4; ++j) {
      int row = rowb + j;
      int qh = row / 14, qw = row - qh * 14;
      const u16* qr = QRW + row * 56;
      #pragma unroll
      for (int nf = 0; nf < 13; ++nf) {
        int ih = qh - khs[nf] + 13; ih = (ih < 0) ? 0 : ih;
        int iw = 27 + qw - kws[nf] + 13;
        float sv = s[nf][j] + b2f(qr[ih]) + b2f(qr[iw]);
        s[nf][j] = (nf * 16 + r16 < 196) ? sv : -1e30f;
      }
    }
    float mrow[4], den[4];
    #pragma unroll
    for (int j = 0; j < 4; ++j) {
      float mm = s[0][j];
      #pragma unroll
      for (int nf = 1; nf < 13; ++nf) mm = fmaxf(mm, s[nf][j]);
      #pragma unroll
      for (int off = 1; off < 16; off <<= 1) mm = fmaxf(mm, __shfl_xor(mm, off));
      mrow[j] = mm; den[j] = 0.f;
    }
    #pragma unroll
    for (int nf = 0; nf < 13; ++nf) {
      #pragma unroll
      for (int j = 0; j < 4; ++j) {
        float p = __expf(s[nf][j] - mrow[j]);
        den[j] += p;
        Pw[(q4 * 4 + j) * 232 + nf * 16 + r16] = f2b(p);
      }
    }
    #pragma unroll
    for (int j = 0; j < 4; ++j)
      #pragma unroll
      for (int off = 1; off < 16; off <<= 1) den[j] += __shfl_xor(den[j], off);
    f32x4 o[3] = {};
    #pragma unroll
    for (int ks = 0; ks < 7; ++ks) {
      bf16x8 ap = *reinterpret_cast<const bf16x8*>(Pw + r16 * 232 + ks * 32 + q4 * 8);
      #pragma unroll
      for (int nf3 = 0; nf3 < 3; ++nf3) {
        bf16x8 bv = *reinterpret_cast<const bf16x8*>(VT + (nf3 * 16 + r16) * 232 + ks * 32 + q4 * 8);
        o[nf3] = MFMA16(ap, bv, o[nf3]);
      }
    }
    #pragma unroll
    for (int j = 0; j < 4; ++j) {
      int row = rowb + j;
      if (row < 196) {
        float rden = 1.f / den[j];
        int rh = row / 14;
        int h = wh * 14 + rh, w = wwn * 14 + row - rh * 14;
        u16* op = obuf + ((size_t)(bI * 56 + h) * 56 + w) * 384 + nhI * 48;
        #pragma unroll
        for (int nf3 = 0; nf3 < 3; ++nf3) {
          int col = nf3 * 16 + r16;
          op[col] = f2b(o[nf3][j] * rden + b2f(QL[row * 72 + col]));
        }
      }
    }
  }
}

extern "C" void kernel_launch(void* const* d_in, const int* in_sizes, int n_in,
                              void* d_out, int out_size, void* d_ws, size_t ws_size,
                              hipStream_t stream) {
  const float* x1      = (const float*)d_in[0];
  const float* x2      = (const float*)d_in[1];
  const float* norm1_w = (const float*)d_in[2];
  const float* norm1_b = (const float*)d_in[3];
  const float* qkv_w   = (const float*)d_in[4];
  const float* qkv_b   = (const float*)d_in[5];
  const float* poolq_w = (const float*)d_in[6];
  const float* poolk_w = (const float*)d_in[7];
  const float* poolv_w = (const float*)d_in[8];
  const float* nq_w    = (const float*)d_in[9];
  const float* nq_b    = (const float*)d_in[10];
  const float* nk_w    = (const float*)d_in[11];
  const float* nk_b    = (const float*)d_in[12];
  const float* nv_w    = (const float*)d_in[13];
  const float* nv_b    = (const float*)d_in[14];
  const float* rel_h   = (const float*)d_in[15];
  const float* rel_w   = (const float*)d_in[16];
  const float* proj_w  = (const float*)d_in[17];
  const float* proj_b  = (const float*)d_in[18];
  const float* norm2_w = (const float*)d_in[19];
  const float* norm2_b = (const float*)d_in[20];
  const float* fc1_w   = (const float*)d_in[21];
  const float* fc1_b   = (const float*)d_in[22];
  const float* fc2_w   = (const float*)d_in[23];
  const float* fc2_b   = (const float*)d_in[24];

  // ws overlay (u16 units). Peak = 57,802,752 u16 = 115.6 MB
  u16* ws      = (u16*)d_ws;
  u16* qkv     = ws;                  // [0, 28901376)   qkv bf16, [3,64,3136,48]
  u16* xn      = ws + 28901376;       // LN(x1) bf16
  u16* qkvc    = ws + 28901376;       // post conv+LN (after xn dead)
  u16* obuf    = ws;                  // attn out bf16 [B,H,W,384]
  u16* h1      = ws;                  // gelu(fc1) bf16
  u16* yn      = ws + 48168960;       // LN(y1) bf16
  u16* qkv_wt  = ws + 38535168;       // bf16 [1152][384] (dies at step 3)
  u16* proj_wt = ws + 9633792;        // bf16 [384][384]  (after qkv dead)
  u16* fc1_wt  = ws + 38535168;       // bf16 [1536][384] (after qkvc dead)
  u16* fc2_wt  = ws + 39124992;       // bf16 [384][1536]
  float* y1 = (float*)d_out;          // 9633792 f32
  float* y2 = y1 + 9633792;

  // 0a. convert qkv weights (transposed [N][K] bf16)
  wcvt_kernel<<<(384*1152 + 255)/256, 256, 0, stream>>>(qkv_w, qkv_wt, 384, 1152);
  // 1. xn = LN(x1)
  ln384_kernel<<<NTOK / 4, 256, 0, stream>>>(x1, norm1_w, norm1_b, xn);
  // 2. qkv = xn @ qkv_w + qkv_b  (MFMA, scattered layout)
  mgemm_kernel<0><<<dim3(196, 9), 256, 0, stream>>>(xn, qkv_wt, qkv_b, nullptr, qkv, NTOK, 1152, 384);
  // 3. q/k/v = LN(dwconv3x3(qkv))  (thread-per-pixel)
  convln_kernel<<<dim3(13, 192), 256, 0, stream>>>(qkv, poolq_w, poolk_w, poolv_w,
                                                   nq_w, nq_b, nk_w, nk_b, nv_w, nv_b, qkvc);
  // 0b. convert proj weights (qkv region now dead)
  wcvt_kernel<<<(384*384 + 255)/256, 256, 0, stream>>>(proj_w, proj_wt, 384, 384);
  // 4. MFMA window attention (+ ori_q residual), permuted to [B,H,W,384]
  attn_kernel<<<1024, 256, 0, stream>>>(qkvc, rel_h, rel_w, obuf);
  // 0c. convert mlp weights (qkvc region now dead)
  wcvt_kernel<<<(384*1536 + 255)/256, 256, 0, stream>>>(fc1_w, fc1_wt, 384, 1536);
  wcvt_kernel<<<(1536*384 + 255)/256, 256, 0, stream>>>(fc2_w, fc2_wt, 1536, 384);
  // 5. y1 = x1 + obuf @ proj_w + proj_b
  mgemm_kernel<1><<<dim3(196, 3), 256, 0, stream>>>(obuf, proj_wt, proj_b, x1, y1, NTOK, 384, 384);
  // 6. yn = LN(y1)
  ln384_kernel<<<NTOK / 4, 256, 0, stream>>>(y1, norm2_w, norm2_b, yn);
  // 7. h1 = gelu(yn @ fc1_w + fc1_b)
  mgemm_kernel<2><<<dim3(196, 12), 256, 0, stream>>>(yn, fc1_wt, fc1_b, nullptr, h1, NTOK, 1536, 384);
  // 8. y2 = x2 + h1 @ fc2_w + fc2_b
  mgemm_kernel<1><<<dim3(196, 3), 256, 0, stream>>>(h1, fc2_wt, fc2_b, x2, y2, NTOK, 384, 1536);
}

// Round 6
// 447.686 us; speedup vs baseline: 4.3163x; 1.0097x over previous
//
#include <hip/hip_runtime.h>
#include <hip/hip_bf16.h>

typedef unsigned short u16;
typedef unsigned int u32;

#define DEVI __device__ __forceinline__

constexpr int BB = 8, HHc = 56, WWc = 56, DIMC = 384, NHC = 8, HDC = 48, WSZ = 14;
constexpr int NTOK = BB * HHc * WWc;          // 25088
constexpr int HIDC = 4 * DIMC;                // 1536
constexpr float EPSF = 1e-5f;
constexpr float SCALEF = 0.14433756729740643f;   // 48^-0.5

typedef short bf16x8 __attribute__((ext_vector_type(8)));
typedef float f32x4 __attribute__((ext_vector_type(4)));

// ---- bf16 helpers (raw ushort view) ----
DEVI float b2f(u16 u) { u32 x = ((u32)u) << 16; float f; __builtin_memcpy(&f, &x, 4); return f; }
DEVI float uasf(u32 x) { float f; __builtin_memcpy(&f, &x, 4); return f; }
DEVI u16 f2b(float f) {
  u32 x; __builtin_memcpy(&x, &f, 4);
  u32 r = (x >> 16) & 1u; x += 0x7fffu + r;
  return (u16)(x >> 16);
}

DEVI float wred_sum(float v) {
  #pragma unroll
  for (int o = 32; o; o >>= 1) v += __shfl_xor(v, o);
  return v;
}

// async global->LDS, 16B per lane; dest = uniform base + lane*16
#define GLOAD_LDS16(g, l) __builtin_amdgcn_global_load_lds( \
    (const __attribute__((address_space(1))) u32*)(g), \
    (__attribute__((address_space(3))) u32*)(l), 16, 0, 0)

// ---- weight convert f32 [K][N] -> bf16 [N][K] (transpose) ----
__global__ __launch_bounds__(256)
void wcvt_kernel(const float* __restrict__ in, u16* __restrict__ out, int K, int N) {
  int id = blockIdx.x * 256 + threadIdx.x;
  if (id >= K * N) return;
  int n = id / K, k = id - n * K;
  out[id] = f2b(in[(size_t)k * N + n]);
}

// ---- LayerNorm over 384: f32 in -> bf16 out (one wave per token) ----
__global__ __launch_bounds__(256)
void ln384_kernel(const float* __restrict__ x, const float* __restrict__ w,
                  const float* __restrict__ b, u16* __restrict__ out) {
  int wave = threadIdx.x >> 6, lane = threadIdx.x & 63;
  int tok = blockIdx.x * 4 + wave;
  if (tok >= NTOK) return;
  const float* xr = x + (size_t)tok * DIMC;
  float v[6]; float s = 0.f, ss = 0.f;
  #pragma unroll
  for (int i = 0; i < 6; ++i) {
    v[i] = xr[lane + i * 64];
    s += v[i]; ss += v[i] * v[i];
  }
  s = wred_sum(s); ss = wred_sum(ss);
  float mean = s * (1.f / 384.f);
  float var = ss * (1.f / 384.f) - mean * mean;
  float inv = rsqrtf(var + EPSF);
  u16* orow = out + (size_t)tok * DIMC;
  #pragma unroll
  for (int i = 0; i < 6; ++i) {
    int c = lane + i * 64;
    orow[c] = f2b((v[i] - mean) * inv * w[c] + b[c]);
  }
}

// ---- MFMA GEMM: C[M,N] = A(bf16)[M,K] @ Wt(bf16,[N][K])^T + bias ----
// 128x128 tile, BK=32, 4 waves; global_load_lds(16B) staging, swizzled slots.
// MODE 0: scatter bf16 to qkv layout [3, B*NH, 56*56, 48]
// MODE 1: f32 out = v + res (f32 residual), row-major
// MODE 2: bf16 out = GELU(exact)(v), row-major
template<int MODE>
__global__ __launch_bounds__(256)
void mgemm_kernel(const u16* __restrict__ A, const u16* __restrict__ Wt,
                  const float* __restrict__ bias, const float* __restrict__ res,
                  void* __restrict__ outv, int M, int N, int K) {
  __shared__ __attribute__((aligned(16))) u16 As[128 * 32];
  __shared__ __attribute__((aligned(16))) u16 Bs[128 * 32];
  int tid = threadIdx.x;
  int wave = tid >> 6, lane = tid & 63;
  int wr = wave >> 1, wc = wave & 1;
  int bm0 = blockIdx.x * 128, bn0 = blockIdx.y * 128;
  // staging: wave w owns rows [w*32, w*32+32) of both tiles; lane l -> row l>>2,
  // LDS slot l&3; global slot pre-swizzled so ds_read can XOR-deswizzle.
  int lrow = lane >> 2;
  int slot = (lane & 3) ^ ((lane >> 3) & 3);
  const u16* ag0 = A  + (size_t)(bm0 + wave * 32 + lrow) * K + slot * 8;
  const u16* ag1 = ag0 + (size_t)16 * K;
  const u16* bg0 = Wt + (size_t)(bn0 + wave * 32 + lrow) * K + slot * 8;
  const u16* bg1 = bg0 + (size_t)16 * K;
  u16* as0 = As + wave * 32 * 32;
  u16* as1 = as0 + 16 * 32;
  u16* bs0 = Bs + wave * 32 * 32;
  u16* bs1 = bs0 + 16 * 32;
  int q4 = lane >> 4, r16 = lane & 15;
  int rslot = (q4 ^ ((r16 >> 1) & 3)) * 8;        // de-swizzle on read
  const u16* ar = As + (wr * 64 + r16) * 32 + rslot;
  const u16* br = Bs + (wc * 64 + r16) * 32 + rslot;
  f32x4 acc[4][4] = {};
  for (int k0 = 0; k0 < K; k0 += 32) {
    GLOAD_LDS16(ag0 + k0, as0);
    GLOAD_LDS16(ag1 + k0, as1);
    GLOAD_LDS16(bg0 + k0, bs0);
    GLOAD_LDS16(bg1 + k0, bs1);
    __syncthreads();                               // drains vmcnt, LDS ready
    bf16x8 af[4], bf[4];
    #pragma unroll
    for (int f = 0; f < 4; ++f) {
      af[f] = *reinterpret_cast<const bf16x8*>(ar + f * 16 * 32);
      bf[f] = *reinterpret_cast<const bf16x8*>(br + f * 16 * 32);
    }
    #pragma unroll
    for (int fm = 0; fm < 4; ++fm)
      #pragma unroll
      for (int fn = 0; fn < 4; ++fn)
        acc[fm][fn] = __builtin_amdgcn_mfma_f32_16x16x32_bf16(af[fm], bf[fn], acc[fm][fn], 0, 0, 0);
    __syncthreads();                               // compute done before overwrite
  }
  // epilogue: D layout col=lane&15, row=(lane>>4)*4+j
  int c0 = bn0 + wc * 64 + r16;
  int r0 = bm0 + wr * 64 + q4 * 4;
  #pragma unroll
  for (int fm = 0; fm < 4; ++fm) {
    #pragma unroll
    for (int fn = 0; fn < 4; ++fn) {
      int c = c0 + fn * 16;
      float bsv = bias[c];
      #pragma unroll
      for (int j = 0; j < 4; ++j) {
        int r = r0 + fm * 16 + j;
        float v = acc[fm][fn][j] + bsv;
        if constexpr (MODE == 0) {
          u16* out = (u16*)outv;
          int s = c / DIMC; int rem = c - s * DIMC;
          int nh = rem / HDC; int ch = rem - nh * HDC;
          int b = r / 3136; int hw = r - b * 3136;
          out[(((size_t)(s * 64 + b * 8 + nh)) * 3136 + hw) * 48 + ch] = f2b(v);
        } else if constexpr (MODE == 1) {
          float* out = (float*)outv;
          size_t idx = (size_t)r * N + c;
          out[idx] = v + res[idx];
        } else {
          u16* out = (u16*)outv;
          size_t idx = (size_t)r * N + c;
          out[idx] = f2b(0.5f * v * (1.0f + erff(v * 0.70710678118654752440f)));
        }
      }
    }
  }
}

// ---- depthwise 3x3 conv (pad 1) + LayerNorm over 48 channels ----
// thread-per-pixel: vectorized loads, in-register LN, LDS-staged weights
__global__ __launch_bounds__(256)
void convln_kernel(const u16* __restrict__ qkv,
                   const float* __restrict__ wq, const float* __restrict__ wk, const float* __restrict__ wv,
                   const float* __restrict__ gq, const float* __restrict__ bq,
                   const float* __restrict__ gk, const float* __restrict__ bk,
                   const float* __restrict__ gv, const float* __restrict__ bv,
                   u16* __restrict__ out) {
  __shared__ __attribute__((aligned(16))) float wsm[432];
  __shared__ __attribute__((aligned(16))) float gsm[48];
  __shared__ __attribute__((aligned(16))) float bsm[48];
  int tid = threadIdx.x;
  int sb = blockIdx.y;                  // 0..191 = s*64 + bnh
  int s = sb >> 6;
  const float* wgt = (s == 0) ? wq : ((s == 1) ? wk : wv);
  const float* gam = (s == 0) ? gq : ((s == 1) ? gk : gv);
  const float* bet = (s == 0) ? bq : ((s == 1) ? bk : bv);
  for (int i = tid; i < 432; i += 256) wsm[i] = wgt[i];
  if (tid < 48) { gsm[tid] = gam[tid]; bsm[tid] = bet[tid]; }
  __syncthreads();
  int hw = blockIdx.x * 256 + tid;
  if (hw >= 3136) return;
  int h = hw / 56, w = hw - h * 56;
  const u16* img = qkv + (size_t)sb * (3136 * 48);
  float acc[48];
  #pragma unroll
  for (int c = 0; c < 48; ++c) acc[c] = 0.f;
  #pragma unroll
  for (int dy = -1; dy <= 1; ++dy) {
    int hh = h + dy;
    if ((unsigned)hh >= 56u) continue;
    #pragma unroll
    for (int dx = -1; dx <= 1; ++dx) {
      int ww = w + dx;
      if ((unsigned)ww >= 56u) continue;
      const uint4* p = reinterpret_cast<const uint4*>(img + (size_t)(hh * 56 + ww) * 48);
      const float4* wr = reinterpret_cast<const float4*>(wsm + ((dy + 1) * 3 + (dx + 1)) * 48);
      #pragma unroll
      for (int g = 0; g < 6; ++g) {
        uint4 v = p[g];
        float4 w0 = wr[g * 2], w1 = wr[g * 2 + 1];
        acc[g * 8 + 0] += uasf(v.x << 16)          * w0.x;
        acc[g * 8 + 1] += uasf(v.x & 0xFFFF0000u)  * w0.y;
        acc[g * 8 + 2] += uasf(v.y << 16)          * w0.z;
        acc[g * 8 + 3] += uasf(v.y & 0xFFFF0000u)  * w0.w;
        acc[g * 8 + 4] += uasf(v.z << 16)          * w1.x;
        acc[g * 8 + 5] += uasf(v.z & 0xFFFF0000u)  * w1.y;
        acc[g * 8 + 6] += uasf(v.w << 16)          * w1.z;
        acc[g * 8 + 7] += uasf(v.w & 0xFFFF0000u)  * w1.w;
      }
    }
  }
  float sum = 0.f, ssq = 0.f;
  #pragma unroll
  for (int c = 0; c < 48; ++c) { sum += acc[c]; ssq += acc[c] * acc[c]; }
  float mean = sum * (1.f / 48.f);
  float var = ssq * (1.f / 48.f) - mean * mean;
  float inv = rsqrtf(var + EPSF);
  u16* op = out + ((size_t)sb * 3136 + hw) * 48;
  #pragma unroll
  for (int g = 0; g < 6; ++g) {
    const float4 gm0 = *reinterpret_cast<const float4*>(gsm + g * 8);
    const float4 gm1 = *reinterpret_cast<const float4*>(gsm + g * 8 + 4);
    const float4 bt0 = *reinterpret_cast<const float4*>(bsm + g * 8);
    const float4 bt1 = *reinterpret_cast<const float4*>(bsm + g * 8 + 4);
    uint4 ov;
    u32 a0 = f2b((acc[g * 8 + 0] - mean) * inv * gm0.x + bt0.x);
    u32 a1 = f2b((acc[g * 8 + 1] - mean) * inv * gm0.y + bt0.y);
    u32 a2 = f2b((acc[g * 8 + 2] - mean) * inv * gm0.z + bt0.z);
    u32 a3 = f2b((acc[g * 8 + 3] - mean) * inv * gm0.w + bt0.w);
    u32 a4 = f2b((acc[g * 8 + 4] - mean) * inv * gm1.x + bt1.x);
    u32 a5 = f2b((acc[g * 8 + 5] - mean) * inv * gm1.y + bt1.y);
    u32 a6 = f2b((acc[g * 8 + 6] - mean) * inv * gm1.z + bt1.z);
    u32 a7 = f2b((acc[g * 8 + 7] - mean) * inv * gm1.w + bt1.w);
    ov.x = a0 | (a1 << 16);
    ov.y = a2 | (a3 << 16);
    ov.z = a4 | (a5 << 16);
    ov.w = a6 | (a7 << 16);
    *reinterpret_cast<uint4*>(op + g * 8) = ov;
  }
}

// ---- MFMA window attention: one block (8 waves, 512 thr) per window ----
// LDS: K[208][72] (pre-scaled), V^T[48][232], QRW[208][56] bias tables,
//      PB = Rel staging / 8 per-wave P tiles [16][224]. Q read from global.
#define MFMA16(a, b, c) __builtin_amdgcn_mfma_f32_16x16x32_bf16((a), (b), (c), 0, 0, 0)
constexpr int LDP = 224;
__global__ __launch_bounds__(512)
void attn_kernel(const u16* __restrict__ qkvc, const float* __restrict__ rel_h,
                 const float* __restrict__ rel_w, u16* __restrict__ obuf) {
  __shared__ __attribute__((aligned(16))) u16 KL[208 * 72];
  __shared__ __attribute__((aligned(16))) u16 VT[48 * 232];
  __shared__ __attribute__((aligned(16))) u16 QRW[208 * 56];
  __shared__ __attribute__((aligned(16))) u16 PB[8 * 16 * LDP];

  int wid = blockIdx.x;
  int bnh = wid >> 4, wrem = wid & 15, wh = wrem >> 2, wwn = wrem & 3;
  int tid = threadIdx.x;
  int wave = tid >> 6, lane = tid & 63;
  int q4 = lane >> 4, r16 = lane & 15;

  { u32* z;
    z = (u32*)KL; for (int i = tid; i < 208 * 72 / 2; i += 512) z[i] = 0;
    z = (u32*)VT; for (int i = tid; i < 48 * 232 / 2; i += 512) z[i] = 0;
    z = (u32*)PB; for (int i = tid; i < 8 * 16 * LDP / 2; i += 512) z[i] = 0;
  }
  __syncthreads();
  size_t qbase = (size_t)bnh * 3136 * 48;
  size_t kbase = ((size_t)(64 + bnh) * 3136) * 48;
  size_t vbase = ((size_t)(128 + bnh) * 3136) * 48;
  for (int i = tid; i < 196 * 12; i += 512) {
    int r = i / 12, c4 = (i - r * 12) * 4;
    int h = wh * 14 + r / 14, w = wwn * 14 + r % 14;
    size_t g = (size_t)(h * 56 + w) * 48 + c4;
    ushort4 kv = *reinterpret_cast<const ushort4*>(qkvc + kbase + g);
    kv.x = f2b(b2f(kv.x) * SCALEF); kv.y = f2b(b2f(kv.y) * SCALEF);
    kv.z = f2b(b2f(kv.z) * SCALEF); kv.w = f2b(b2f(kv.w) * SCALEF);
    *reinterpret_cast<ushort4*>(KL + r * 72 + c4) = kv;
    ushort4 vv = *reinterpret_cast<const ushort4*>(qkvc + vbase + g);
    VT[(c4 + 0) * 232 + r] = vv.x; VT[(c4 + 1) * 232 + r] = vv.y;
    VT[(c4 + 2) * 232 + r] = vv.z; VT[(c4 + 3) * 232 + r] = vv.w;
  }
  for (int i = tid; i < 54 * 48; i += 512) {
    int r = i / 48, c = i - r * 48;
    float v = (r < 27) ? rel_h[r * 48 + c] : rel_w[(r - 27) * 48 + c];
    PB[r * 72 + c] = f2b(v);            // Rel rows 0..26 = Rh, 27..53 = Rw
  }
  __syncthreads();
  // QRW = Q @ Rel^T (Q frags straight from global; clamp pad rows)
  for (int mf = wave; mf < 13; mf += 8) {
    int qrow = mf * 16 + r16; int qc = qrow < 196 ? qrow : 195;
    int hq = wh * 14 + qc / 14, wq = wwn * 14 + qc % 14;
    const u16* qpg = qkvc + qbase + (size_t)(hq * 56 + wq) * 48;
    bf16x8 af0 = *reinterpret_cast<const bf16x8*>(qpg + q4 * 8);
    bf16x8 af1 = *reinterpret_cast<const bf16x8*>(qpg + 32 + q4 * 8);
    #pragma unroll
    for (int nf = 0; nf < 4; ++nf) {
      bf16x8 b0 = *reinterpret_cast<const bf16x8*>(PB + (nf * 16 + r16) * 72 + q4 * 8);
      bf16x8 b1 = *reinterpret_cast<const bf16x8*>(PB + (nf * 16 + r16) * 72 + 32 + q4 * 8);
      f32x4 acc = {};
      acc = MFMA16(af0, b0, acc);
      acc = MFMA16(af1, b1, acc);
      int col = nf * 16 + r16;
      if (col < 54) {
        #pragma unroll
        for (int j = 0; j < 4; ++j)
          QRW[(mf * 16 + q4 * 4 + j) * 56 + col] = f2b(acc[j]);
      }
    }
  }
  __syncthreads();   // Rel fully consumed before P tiles clobber PB
  u16* Pw = PB + wave * 16 * LDP;
  for (int i = lane; i < 16 * 16; i += 64) {
    int r = i >> 4;
    Pw[r * LDP + 208 + (i & 15)] = 0;
  }
  int khs[13], kws[13];
  #pragma unroll
  for (int nf = 0; nf < 13; ++nf) {
    int key = nf * 16 + r16;
    khs[nf] = key / 14;
    kws[nf] = key - khs[nf] * 14;
  }
  int bI = bnh >> 3, nhI = bnh & 7;
  for (int mf = wave; mf < 13; mf += 8) {
    int qrow = mf * 16 + r16; int qc = qrow < 196 ? qrow : 195;
    int hq = wh * 14 + qc / 14, wq = wwn * 14 + qc % 14;
    const u16* qpg = qkvc + qbase + (size_t)(hq * 56 + wq) * 48;
    bf16x8 af0 = *reinterpret_cast<const bf16x8*>(qpg + q4 * 8);
    bf16x8 af1 = *reinterpret_cast<const bf16x8*>(qpg + 32 + q4 * 8);
    f32x4 s[13];
    #pragma unroll
    for (int nf = 0; nf < 13; ++nf) {
      bf16x8 b0 = *reinterpret_cast<const bf16x8*>(KL + (nf * 16 + r16) * 72 + q4 * 8);
      bf16x8 b1 = *reinterpret_cast<const bf16x8*>(KL + (nf * 16 + r16) * 72 + 32 + q4 * 8);
      f32x4 a = {};
      a = MFMA16(af0, b0, a);
      a = MFMA16(af1, b1, a);
      s[nf] = a;
    }
    int rowb = mf * 16 + q4 * 4;
    #pragma unroll
    for (int j = 0; j < 4; ++j) {
      int row = rowb + j;
      int qh = row / 14, qw = row - qh * 14;
      const u16* qr = QRW + row * 56;
      #pragma unroll
      for (int nf = 0; nf < 13; ++nf) {
        int ih = qh - khs[nf] + 13; ih = (ih < 0) ? 0 : ih;
        int iw = 27 + qw - kws[nf] + 13;
        float sv = s[nf][j] + b2f(qr[ih]) + b2f(qr[iw]);
        s[nf][j] = (nf * 16 + r16 < 196) ? sv : -1e30f;
      }
    }
    float mrow[4], den[4];
    #pragma unroll
    for (int j = 0; j < 4; ++j) {
      float mm = s[0][j];
      #pragma unroll
      for (int nf = 1; nf < 13; ++nf) mm = fmaxf(mm, s[nf][j]);
      #pragma unroll
      for (int off = 1; off < 16; off <<= 1) mm = fmaxf(mm, __shfl_xor(mm, off));
      mrow[j] = mm; den[j] = 0.f;
    }
    #pragma unroll
    for (int nf = 0; nf < 13; ++nf) {
      #pragma unroll
      for (int j = 0; j < 4; ++j) {
        float p = __expf(s[nf][j] - mrow[j]);
        den[j] += p;
        Pw[(q4 * 4 + j) * LDP + nf * 16 + r16] = f2b(p);
      }
    }
    #pragma unroll
    for (int j = 0; j < 4; ++j)
      #pragma unroll
      for (int off = 1; off < 16; off <<= 1) den[j] += __shfl_xor(den[j], off);
    f32x4 o[3] = {};
    #pragma unroll
    for (int ks = 0; ks < 7; ++ks) {
      bf16x8 ap = *reinterpret_cast<const bf16x8*>(Pw + r16 * LDP + ks * 32 + q4 * 8);
      #pragma unroll
      for (int nf3 = 0; nf3 < 3; ++nf3) {
        bf16x8 bv = *reinterpret_cast<const bf16x8*>(VT + (nf3 * 16 + r16) * 232 + ks * 32 + q4 * 8);
        o[nf3] = MFMA16(ap, bv, o[nf3]);
      }
    }
    #pragma unroll
    for (int j = 0; j < 4; ++j) {
      int row = rowb + j;
      if (row < 196) {
        float rden = 1.f / den[j];
        int rh = row / 14;
        int h = wh * 14 + rh, w = wwn * 14 + row - rh * 14;
        const u16* qg = qkvc + qbase + (size_t)(h * 56 + w) * 48;
        u16* op = obuf + ((size_t)(bI * 56 + h) * 56 + w) * 384 + nhI * 48;
        #pragma unroll
        for (int nf3 = 0; nf3 < 3; ++nf3) {
          int col = nf3 * 16 + r16;
          op[col] = f2b(o[nf3][j] * rden + b2f(qg[col]));
        }
      }
    }
  }
}

extern "C" void kernel_launch(void* const* d_in, const int* in_sizes, int n_in,
                              void* d_out, int out_size, void* d_ws, size_t ws_size,
                              hipStream_t stream) {
  const float* x1      = (const float*)d_in[0];
  const float* x2      = (const float*)d_in[1];
  const float* norm1_w = (const float*)d_in[2];
  const float* norm1_b = (const float*)d_in[3];
  const float* qkv_w   = (const float*)d_in[4];
  const float* qkv_b   = (const float*)d_in[5];
  const float* poolq_w = (const float*)d_in[6];
  const float* poolk_w = (const float*)d_in[7];
  const float* poolv_w = (const float*)d_in[8];
  const float* nq_w    = (const float*)d_in[9];
  const float* nq_b    = (const float*)d_in[10];
  const float* nk_w    = (const float*)d_in[11];
  const float* nk_b    = (const float*)d_in[12];
  const float* nv_w    = (const float*)d_in[13];
  const float* nv_b    = (const float*)d_in[14];
  const float* rel_h   = (const float*)d_in[15];
  const float* rel_w   = (const float*)d_in[16];
  const float* proj_w  = (const float*)d_in[17];
  const float* proj_b  = (const float*)d_in[18];
  const float* norm2_w = (const float*)d_in[19];
  const float* norm2_b = (const float*)d_in[20];
  const float* fc1_w   = (const float*)d_in[21];
  const float* fc1_b   = (const float*)d_in[22];
  const float* fc2_w   = (const float*)d_in[23];
  const float* fc2_b   = (const float*)d_in[24];

  // ws overlay (u16 units). Peak = 57,802,752 u16 = 115.6 MB
  u16* ws      = (u16*)d_ws;
  u16* qkv     = ws;                  // [0, 28901376)   qkv bf16, [3,64,3136,48]
  u16* xn      = ws + 28901376;       // LN(x1) bf16
  u16* qkvc    = ws + 28901376;       // post conv+LN (after xn dead)
  u16* obuf    = ws;                  // attn out bf16 [B,H,W,384]
  u16* h1      = ws;                  // gelu(fc1) bf16
  u16* yn      = ws + 48168960;       // LN(y1) bf16
  u16* qkv_wt  = ws + 38535168;       // bf16 [1152][384] (dies at step 3)
  u16* proj_wt = ws + 9633792;        // bf16 [384][384]  (after qkv dead)
  u16* fc1_wt  = ws + 38535168;       // bf16 [1536][384] (after qkvc dead)
  u16* fc2_wt  = ws + 39124992;       // bf16 [384][1536]
  float* y1 = (float*)d_out;          // 9633792 f32
  float* y2 = y1 + 9633792;

  // 0a. convert qkv weights (transposed [N][K] bf16)
  wcvt_kernel<<<(384*1152 + 255)/256, 256, 0, stream>>>(qkv_w, qkv_wt, 384, 1152);
  // 1. xn = LN(x1)
  ln384_kernel<<<NTOK / 4, 256, 0, stream>>>(x1, norm1_w, norm1_b, xn);
  // 2. qkv = xn @ qkv_w + qkv_b  (MFMA, scattered layout)
  mgemm_kernel<0><<<dim3(196, 9), 256, 0, stream>>>(xn, qkv_wt, qkv_b, nullptr, qkv, NTOK, 1152, 384);
  // 3. q/k/v = LN(dwconv3x3(qkv))  (thread-per-pixel)
  convln_kernel<<<dim3(13, 192), 256, 0, stream>>>(qkv, poolq_w, poolk_w, poolv_w,
                                                   nq_w, nq_b, nk_w, nk_b, nv_w, nv_b, qkvc);
  // 0b. convert proj weights (qkv region now dead)
  wcvt_kernel<<<(384*384 + 255)/256, 256, 0, stream>>>(proj_w, proj_wt, 384, 384);
  // 4. MFMA window attention (+ ori_q residual), permuted to [B,H,W,384]
  attn_kernel<<<1024, 512, 0, stream>>>(qkvc, rel_h, rel_w, obuf);
  // 0c. convert mlp weights (qkvc region now dead)
  wcvt_kernel<<<(384*1536 + 255)/256, 256, 0, stream>>>(fc1_w, fc1_wt, 384, 1536);
  wcvt_kernel<<<(1536*384 + 255)/256, 256, 0, stream>>>(fc2_w, fc2_wt, 1536, 384);
  // 5. y1 = x1 + obuf @ proj_w + proj_b
  mgemm_kernel<1><<<dim3(196, 3), 256, 0, stream>>>(obuf, proj_wt, proj_b, x1, y1, NTOK, 384, 384);
  // 6. yn = LN(y1)
  ln384_kernel<<<NTOK / 4, 256, 0, stream>>>(y1, norm2_w, norm2_b, yn);
  // 7. h1 = gelu(yn @ fc1_w + fc1_b)
  mgemm_kernel<2><<<dim3(196, 12), 256, 0, stream>>>(yn, fc1_wt, fc1_b, nullptr, h1, NTOK, 1536, 384);
  // 8. y2 = x2 + h1 @ fc2_w + fc2_b
  mgemm_kernel<1><<<dim3(196, 3), 256, 0, stream>>>(h1, fc2_wt, fc2_b, x2, y2, NTOK, 384, 1536);
}

// Round 7
// 407.071 us; speedup vs baseline: 4.7469x; 1.0998x over previous
//
#include <hip/hip_runtime.h>
#include <hip/hip_bf16.h>

typedef unsigned short u16;
typedef unsigned int u32;

#define DEVI __device__ __forceinline__

constexpr int BB = 8, HHc = 56, WWc = 56, DIMC = 384, NHC = 8, HDC = 48, WSZ = 14;
constexpr int NTOK = BB * HHc * WWc;          // 25088
constexpr int HIDC = 4 * DIMC;                // 1536
constexpr float EPSF = 1e-5f;
constexpr float SCALEF = 0.14433756729740643f;   // 48^-0.5

typedef short bf16x8 __attribute__((ext_vector_type(8)));
typedef float f32x4 __attribute__((ext_vector_type(4)));

// ---- bf16 helpers (raw ushort view) ----
DEVI float b2f(u16 u) { u32 x = ((u32)u) << 16; float f; __builtin_memcpy(&f, &x, 4); return f; }
DEVI float uasf(u32 x) { float f; __builtin_memcpy(&f, &x, 4); return f; }
DEVI u16 f2b(float f) {
  u32 x; __builtin_memcpy(&x, &f, 4);
  u32 r = (x >> 16) & 1u; x += 0x7fffu + r;
  return (u16)(x >> 16);
}

DEVI float wred_sum(float v) {
  #pragma unroll
  for (int o = 32; o; o >>= 1) v += __shfl_xor(v, o);
  return v;
}

// async global->LDS, 16B per lane; dest = uniform base + lane*16
#define GLOAD_LDS16(g, l) __builtin_amdgcn_global_load_lds( \
    (const __attribute__((address_space(1))) u32*)(g), \
    (__attribute__((address_space(3))) u32*)(l), 16, 0, 0)

// ---- weight convert f32 [K][N] -> bf16 [N][K], LDS-tiled transpose ----
// grid (K/32, N/32), block 256 (32x8)
__global__ __launch_bounds__(256)
void wcvt_kernel(const float* __restrict__ in, u16* __restrict__ out, int K, int N) {
  __shared__ float t[32][33];
  int bk = blockIdx.x * 32, bn = blockIdx.y * 32;
  int tx = threadIdx.x & 31, ty = threadIdx.x >> 5;
  #pragma unroll
  for (int i = 0; i < 32; i += 8)
    t[ty + i][tx] = in[(size_t)(bk + ty + i) * N + bn + tx];
  __syncthreads();
  #pragma unroll
  for (int i = 0; i < 32; i += 8)
    out[(size_t)(bn + ty + i) * K + bk + tx] = f2b(t[tx][ty + i]);
}

// ---- LayerNorm over 384: f32 in -> bf16 out (one wave per token) ----
__global__ __launch_bounds__(256)
void ln384_kernel(const float* __restrict__ x, const float* __restrict__ w,
                  const float* __restrict__ b, u16* __restrict__ out) {
  int wave = threadIdx.x >> 6, lane = threadIdx.x & 63;
  int tok = blockIdx.x * 4 + wave;
  if (tok >= NTOK) return;
  const float* xr = x + (size_t)tok * DIMC;
  float v[6]; float s = 0.f, ss = 0.f;
  #pragma unroll
  for (int i = 0; i < 6; ++i) {
    v[i] = xr[lane + i * 64];
    s += v[i]; ss += v[i] * v[i];
  }
  s = wred_sum(s); ss = wred_sum(ss);
  float mean = s * (1.f / 384.f);
  float var = ss * (1.f / 384.f) - mean * mean;
  float inv = rsqrtf(var + EPSF);
  u16* orow = out + (size_t)tok * DIMC;
  #pragma unroll
  for (int i = 0; i < 6; ++i) {
    int c = lane + i * 64;
    orow[c] = f2b((v[i] - mean) * inv * w[c] + b[c]);
  }
}

// ---- MFMA GEMM: C[M,N] = A(bf16)[M,K] @ Wt(bf16,[N][K])^T + bias ----
// 128x128 tile, BK=32, 4 waves; double-buffered global_load_lds(16B),
// prefetch-next-before-compute, ONE barrier per k-step.
// MODE 0: scatter bf16 to qkv layout [3, B*NH, 56*56, 48]
// MODE 1: f32 out = v + res (f32 residual), row-major
// MODE 2: bf16 out = GELU(exact)(v), row-major
template<int MODE>
__global__ __launch_bounds__(256)
void mgemm_kernel(const u16* __restrict__ A, const u16* __restrict__ Wt,
                  const float* __restrict__ bias, const float* __restrict__ res,
                  void* __restrict__ outv, int M, int N, int K) {
  __shared__ __attribute__((aligned(16))) u16 As[2][128 * 32];
  __shared__ __attribute__((aligned(16))) u16 Bs[2][128 * 32];
  int tid = threadIdx.x;
  int wave = tid >> 6, lane = tid & 63;
  int wr = wave >> 1, wc = wave & 1;
  int bm0 = blockIdx.x * 128, bn0 = blockIdx.y * 128;
  // staging: wave w owns rows [w*32, w*32+32); lane l -> row l>>2, slot l&3
  // (global slot pre-swizzled so ds_read can XOR-deswizzle)
  int lrow = lane >> 2;
  int slot = (lane & 3) ^ ((lane >> 3) & 3);
  const u16* ag0 = A  + (size_t)(bm0 + wave * 32 + lrow) * K + slot * 8;
  const u16* ag1 = ag0 + (size_t)16 * K;
  const u16* bg0 = Wt + (size_t)(bn0 + wave * 32 + lrow) * K + slot * 8;
  const u16* bg1 = bg0 + (size_t)16 * K;
  int q4 = lane >> 4, r16 = lane & 15;
  int rslot = (q4 ^ ((r16 >> 1) & 3)) * 8;        // de-swizzle on read
  int aoff = (wr * 64 + r16) * 32 + rslot;
  int boff = (wc * 64 + r16) * 32 + rslot;
  f32x4 acc[4][4] = {};
  int nk = K >> 5;
  {  // prologue: stage t=0 into buf 0
    u16* a0 = As[0] + wave * 1024;
    u16* b0 = Bs[0] + wave * 1024;
    GLOAD_LDS16(ag0, a0);
    GLOAD_LDS16(ag1, a0 + 512);
    GLOAD_LDS16(bg0, b0);
    GLOAD_LDS16(bg1, b0 + 512);
  }
  __syncthreads();
  int cur = 0;
  for (int t = 0; t < nk; ++t) {
    if (t + 1 < nk) {                              // prefetch next tile (async)
      int k0 = (t + 1) << 5;
      u16* a0 = As[cur ^ 1] + wave * 1024;
      u16* b0 = Bs[cur ^ 1] + wave * 1024;
      GLOAD_LDS16(ag0 + k0, a0);
      GLOAD_LDS16(ag1 + k0, a0 + 512);
      GLOAD_LDS16(bg0 + k0, b0);
      GLOAD_LDS16(bg1 + k0, b0 + 512);
    }
    const u16* ar = As[cur] + aoff;
    const u16* br = Bs[cur] + boff;
    bf16x8 af[4], bf[4];
    #pragma unroll
    for (int f = 0; f < 4; ++f) {
      af[f] = *reinterpret_cast<const bf16x8*>(ar + f * 512);
      bf[f] = *reinterpret_cast<const bf16x8*>(br + f * 512);
    }
    #pragma unroll
    for (int fm = 0; fm < 4; ++fm)
      #pragma unroll
      for (int fn = 0; fn < 4; ++fn)
        acc[fm][fn] = __builtin_amdgcn_mfma_f32_16x16x32_bf16(af[fm], bf[fn], acc[fm][fn], 0, 0, 0);
    __syncthreads();                               // drains vmcnt (prefetch) + lgkm
    cur ^= 1;
  }
  // epilogue: D layout col=lane&15, row=(lane>>4)*4+j
  int c0 = bn0 + wc * 64 + r16;
  int r0 = bm0 + wr * 64 + q4 * 4;
  #pragma unroll
  for (int fm = 0; fm < 4; ++fm) {
    #pragma unroll
    for (int fn = 0; fn < 4; ++fn) {
      int c = c0 + fn * 16;
      float bsv = bias[c];
      #pragma unroll
      for (int j = 0; j < 4; ++j) {
        int r = r0 + fm * 16 + j;
        float v = acc[fm][fn][j] + bsv;
        if constexpr (MODE == 0) {
          u16* out = (u16*)outv;
          int s = c / DIMC; int rem = c - s * DIMC;
          int nh = rem / HDC; int ch = rem - nh * HDC;
          int b = r / 3136; int hw = r - b * 3136;
          out[(((size_t)(s * 64 + b * 8 + nh)) * 3136 + hw) * 48 + ch] = f2b(v);
        } else if constexpr (MODE == 1) {
          float* out = (float*)outv;
          size_t idx = (size_t)r * N + c;
          out[idx] = v + res[idx];
        } else {
          u16* out = (u16*)outv;
          size_t idx = (size_t)r * N + c;
          out[idx] = f2b(0.5f * v * (1.0f + erff(v * 0.70710678118654752440f)));
        }
      }
    }
  }
}

// ---- depthwise 3x3 conv (pad 1) + LayerNorm over 48 channels ----
__global__ __launch_bounds__(256)
void convln_kernel(const u16* __restrict__ qkv,
                   const float* __restrict__ wq, const float* __restrict__ wk, const float* __restrict__ wv,
                   const float* __restrict__ gq, const float* __restrict__ bq,
                   const float* __restrict__ gk, const float* __restrict__ bk,
                   const float* __restrict__ gv, const float* __restrict__ bv,
                   u16* __restrict__ out) {
  __shared__ __attribute__((aligned(16))) float wsm[432];
  __shared__ __attribute__((aligned(16))) float gsm[48];
  __shared__ __attribute__((aligned(16))) float bsm[48];
  int tid = threadIdx.x;
  int sb = blockIdx.y;                  // 0..191 = s*64 + bnh
  int s = sb >> 6;
  const float* wgt = (s == 0) ? wq : ((s == 1) ? wk : wv);
  const float* gam = (s == 0) ? gq : ((s == 1) ? gk : gv);
  const float* bet = (s == 0) ? bq : ((s == 1) ? bk : bv);
  for (int i = tid; i < 432; i += 256) wsm[i] = wgt[i];
  if (tid < 48) { gsm[tid] = gam[tid]; bsm[tid] = bet[tid]; }
  __syncthreads();
  int hw = blockIdx.x * 256 + tid;
  if (hw >= 3136) return;
  int h = hw / 56, w = hw - h * 56;
  const u16* img = qkv + (size_t)sb * (3136 * 48);
  float acc[48];
  #pragma unroll
  for (int c = 0; c < 48; ++c) acc[c] = 0.f;
  #pragma unroll
  for (int dy = -1; dy <= 1; ++dy) {
    int hh = h + dy;
    if ((unsigned)hh >= 56u) continue;
    #pragma unroll
    for (int dx = -1; dx <= 1; ++dx) {
      int ww = w + dx;
      if ((unsigned)ww >= 56u) continue;
      const uint4* p = reinterpret_cast<const uint4*>(img + (size_t)(hh * 56 + ww) * 48);
      const float4* wr = reinterpret_cast<const float4*>(wsm + ((dy + 1) * 3 + (dx + 1)) * 48);
      #pragma unroll
      for (int g = 0; g < 6; ++g) {
        uint4 v = p[g];
        float4 w0 = wr[g * 2], w1 = wr[g * 2 + 1];
        acc[g * 8 + 0] += uasf(v.x << 16)          * w0.x;
        acc[g * 8 + 1] += uasf(v.x & 0xFFFF0000u)  * w0.y;
        acc[g * 8 + 2] += uasf(v.y << 16)          * w0.z;
        acc[g * 8 + 3] += uasf(v.y & 0xFFFF0000u)  * w0.w;
        acc[g * 8 + 4] += uasf(v.z << 16)          * w1.x;
        acc[g * 8 + 5] += uasf(v.z & 0xFFFF0000u)  * w1.y;
        acc[g * 8 + 6] += uasf(v.w << 16)          * w1.z;
        acc[g * 8 + 7] += uasf(v.w & 0xFFFF0000u)  * w1.w;
      }
    }
  }
  float sum = 0.f, ssq = 0.f;
  #pragma unroll
  for (int c = 0; c < 48; ++c) { sum += acc[c]; ssq += acc[c] * acc[c]; }
  float mean = sum * (1.f / 48.f);
  float var = ssq * (1.f / 48.f) - mean * mean;
  float inv = rsqrtf(var + EPSF);
  u16* op = out + ((size_t)sb * 3136 + hw) * 48;
  #pragma unroll
  for (int g = 0; g < 6; ++g) {
    const float4 gm0 = *reinterpret_cast<const float4*>(gsm + g * 8);
    const float4 gm1 = *reinterpret_cast<const float4*>(gsm + g * 8 + 4);
    const float4 bt0 = *reinterpret_cast<const float4*>(bsm + g * 8);
    const float4 bt1 = *reinterpret_cast<const float4*>(bsm + g * 8 + 4);
    uint4 ov;
    u32 a0 = f2b((acc[g * 8 + 0] - mean) * inv * gm0.x + bt0.x);
    u32 a1 = f2b((acc[g * 8 + 1] - mean) * inv * gm0.y + bt0.y);
    u32 a2 = f2b((acc[g * 8 + 2] - mean) * inv * gm0.z + bt0.z);
    u32 a3 = f2b((acc[g * 8 + 3] - mean) * inv * gm0.w + bt0.w);
    u32 a4 = f2b((acc[g * 8 + 4] - mean) * inv * gm1.x + bt1.x);
    u32 a5 = f2b((acc[g * 8 + 5] - mean) * inv * gm1.y + bt1.y);
    u32 a6 = f2b((acc[g * 8 + 6] - mean) * inv * gm1.z + bt1.z);
    u32 a7 = f2b((acc[g * 8 + 7] - mean) * inv * gm1.w + bt1.w);
    ov.x = a0 | (a1 << 16);
    ov.y = a2 | (a3 << 16);
    ov.z = a4 | (a5 << 16);
    ov.w = a6 | (a7 << 16);
    *reinterpret_cast<uint4*>(op + g * 8) = ov;
  }
}

// ---- MFMA window attention: one block (8 waves, 512 thr) per window ----
// LDS: K[208][72] (pre-scaled), V^T[48][232], QRW[208][56] bias tables,
//      PB = Rel staging / 8 per-wave P tiles [16][224] (col-swizzled).
#define MFMA16(a, b, c) __builtin_amdgcn_mfma_f32_16x16x32_bf16((a), (b), (c), 0, 0, 0)
constexpr int LDP = 224;
__global__ __launch_bounds__(512, 2)
void attn_kernel(const u16* __restrict__ qkvc, const float* __restrict__ rel_h,
                 const float* __restrict__ rel_w, u16* __restrict__ obuf) {
  __shared__ __attribute__((aligned(16))) u16 KL[208 * 72];
  __shared__ __attribute__((aligned(16))) u16 VT[48 * 232];
  __shared__ __attribute__((aligned(16))) u16 QRW[208 * 56];
  __shared__ __attribute__((aligned(16))) u16 PB[8 * 16 * LDP];

  int wid = blockIdx.x;
  int bnh = wid >> 4, wrem = wid & 15, wh = wrem >> 2, wwn = wrem & 3;
  int tid = threadIdx.x;
  int wave = tid >> 6, lane = tid & 63;
  int q4 = lane >> 4, r16 = lane & 15;

  { u32* z;
    z = (u32*)KL; for (int i = tid; i < 208 * 72 / 2; i += 512) z[i] = 0;
    z = (u32*)VT; for (int i = tid; i < 48 * 232 / 2; i += 512) z[i] = 0;
    z = (u32*)PB; for (int i = tid; i < 8 * 16 * LDP / 2; i += 512) z[i] = 0;
  }
  __syncthreads();
  size_t qbase = (size_t)bnh * 3136 * 48;
  size_t kbase = ((size_t)(64 + bnh) * 3136) * 48;
  size_t vbase = ((size_t)(128 + bnh) * 3136) * 48;
  for (int i = tid; i < 196 * 12; i += 512) {
    int r = i / 12, c4 = (i - r * 12) * 4;
    int h = wh * 14 + r / 14, w = wwn * 14 + r % 14;
    size_t g = (size_t)(h * 56 + w) * 48 + c4;
    ushort4 kv = *reinterpret_cast<const ushort4*>(qkvc + kbase + g);
    kv.x = f2b(b2f(kv.x) * SCALEF); kv.y = f2b(b2f(kv.y) * SCALEF);
    kv.z = f2b(b2f(kv.z) * SCALEF); kv.w = f2b(b2f(kv.w) * SCALEF);
    *reinterpret_cast<ushort4*>(KL + r * 72 + c4) = kv;
    ushort4 vv = *reinterpret_cast<const ushort4*>(qkvc + vbase + g);
    VT[(c4 + 0) * 232 + r] = vv.x; VT[(c4 + 1) * 232 + r] = vv.y;
    VT[(c4 + 2) * 232 + r] = vv.z; VT[(c4 + 3) * 232 + r] = vv.w;
  }
  for (int i = tid; i < 54 * 48; i += 512) {
    int r = i / 48, c = i - r * 48;
    float v = (r < 27) ? rel_h[r * 48 + c] : rel_w[(r - 27) * 48 + c];
    PB[r * 72 + c] = f2b(v);            // Rel rows 0..26 = Rh, 27..53 = Rw
  }
  __syncthreads();
  // QRW = Q @ Rel^T (Q frags straight from global; clamp pad rows)
  for (int mf = wave; mf < 13; mf += 8) {
    int qrow = mf * 16 + r16; int qc = qrow < 196 ? qrow : 195;
    int hq = wh * 14 + qc / 14, wq = wwn * 14 + qc % 14;
    const u16* qpg = qkvc + qbase + (size_t)(hq * 56 + wq) * 48;
    bf16x8 af0 = *reinterpret_cast<const bf16x8*>(qpg + q4 * 8);
    bf16x8 af1 = *reinterpret_cast<const bf16x8*>(qpg + 32 + q4 * 8);
    #pragma unroll
    for (int nf = 0; nf < 4; ++nf) {
      bf16x8 b0 = *reinterpret_cast<const bf16x8*>(PB + (nf * 16 + r16) * 72 + q4 * 8);
      bf16x8 b1 = *reinterpret_cast<const bf16x8*>(PB + (nf * 16 + r16) * 72 + 32 + q4 * 8);
      f32x4 acc = {};
      acc = MFMA16(af0, b0, acc);
      acc = MFMA16(af1, b1, acc);
      int col = nf * 16 + r16;
      if (col < 54) {
        #pragma unroll
        for (int j = 0; j < 4; ++j)
          QRW[(mf * 16 + q4 * 4 + j) * 56 + col] = f2b(acc[j]);
      }
    }
  }
  __syncthreads();   // Rel fully consumed before P tiles clobber PB
  u16* Pw = PB + wave * 16 * LDP;
  // zero pad cols 208..223 (at their per-row swizzled locations)
  for (int i = lane; i < 16 * 16; i += 64) {
    int r = i >> 4;
    Pw[r * LDP + ((208 + (i & 15)) ^ (((r >> 2) & 3) << 3))] = 0;
  }
  int khs[13], kws[13];
  #pragma unroll
  for (int nf = 0; nf < 13; ++nf) {
    int key = nf * 16 + r16;
    khs[nf] = key / 14;
    kws[nf] = key - khs[nf] * 14;
  }
  int bI = bnh >> 3, nhI = bnh & 7;
  for (int mf = wave; mf < 13; mf += 8) {
    int qrow = mf * 16 + r16; int qc = qrow < 196 ? qrow : 195;
    int hq = wh * 14 + qc / 14, wq = wwn * 14 + qc % 14;
    const u16* qpg = qkvc + qbase + (size_t)(hq * 56 + wq) * 48;
    bf16x8 af0 = *reinterpret_cast<const bf16x8*>(qpg + q4 * 8);
    bf16x8 af1 = *reinterpret_cast<const bf16x8*>(qpg + 32 + q4 * 8);
    f32x4 s[13];
    #pragma unroll
    for (int nf = 0; nf < 13; ++nf) {
      bf16x8 b0 = *reinterpret_cast<const bf16x8*>(KL + (nf * 16 + r16) * 72 + q4 * 8);
      bf16x8 b1 = *reinterpret_cast<const bf16x8*>(KL + (nf * 16 + r16) * 72 + 32 + q4 * 8);
      f32x4 a = {};
      a = MFMA16(af0, b0, a);
      a = MFMA16(af1, b1, a);
      s[nf] = a;
    }
    int rowb = mf * 16 + q4 * 4;
    #pragma unroll
    for (int j = 0; j < 4; ++j) {
      int row = rowb + j;
      int qh = row / 14, qw = row - qh * 14;
      const u16* qr = QRW + row * 56;
      #pragma unroll
      for (int nf = 0; nf < 13; ++nf) {
        int ih = qh - khs[nf] + 13; ih = (ih < 0) ? 0 : ih;
        int iw = 27 + qw - kws[nf] + 13;
        float sv = s[nf][j] + b2f(qr[ih]) + b2f(qr[iw]);
        s[nf][j] = (nf * 16 + r16 < 196) ? sv : -1e30f;
      }
    }
    float mrow[4], den[4];
    #pragma unroll
    for (int j = 0; j < 4; ++j) {
      float mm = s[0][j];
      #pragma unroll
      for (int nf = 1; nf < 13; ++nf) mm = fmaxf(mm, s[nf][j]);
      #pragma unroll
      for (int off = 1; off < 16; off <<= 1) mm = fmaxf(mm, __shfl_xor(mm, off));
      mrow[j] = mm; den[j] = 0.f;
    }
    // P store: col' = col ^ (q4<<3) spreads the 4 row-groups across 2 bank groups
    #pragma unroll
    for (int nf = 0; nf < 13; ++nf) {
      #pragma unroll
      for (int j = 0; j < 4; ++j) {
        float p = __expf(s[nf][j] - mrow[j]);
        den[j] += p;
        Pw[(q4 * 4 + j) * LDP + (((nf * 16 + r16) ^ (q4 << 3)))] = f2b(p);
      }
    }
    #pragma unroll
    for (int j = 0; j < 4; ++j)
      #pragma unroll
      for (int off = 1; off < 16; off <<= 1) den[j] += __shfl_xor(den[j], off);
    f32x4 o[3] = {};
    #pragma unroll
    for (int ks = 0; ks < 7; ++ks) {
      bf16x8 ap = *reinterpret_cast<const bf16x8*>(
          Pw + r16 * LDP + ((ks * 32 + q4 * 8) ^ (((r16 >> 2) & 3) << 3)));
      #pragma unroll
      for (int nf3 = 0; nf3 < 3; ++nf3) {
        bf16x8 bv = *reinterpret_cast<const bf16x8*>(VT + (nf3 * 16 + r16) * 232 + ks * 32 + q4 * 8);
        o[nf3] = MFMA16(ap, bv, o[nf3]);
      }
    }
    #pragma unroll
    for (int j = 0; j < 4; ++j) {
      int row = rowb + j;
      if (row < 196) {
        float rden = 1.f / den[j];
        int rh = row / 14;
        int h = wh * 14 + rh, w = wwn * 14 + row - rh * 14;
        const u16* qg = qkvc + qbase + (size_t)(h * 56 + w) * 48;
        u16* op = obuf + ((size_t)(bI * 56 + h) * 56 + w) * 384 + nhI * 48;
        #pragma unroll
        for (int nf3 = 0; nf3 < 3; ++nf3) {
          int col = nf3 * 16 + r16;
          op[col] = f2b(o[nf3][j] * rden + b2f(qg[col]));
        }
      }
    }
  }
}

extern "C" void kernel_launch(void* const* d_in, const int* in_sizes, int n_in,
                              void* d_out, int out_size, void* d_ws, size_t ws_size,
                              hipStream_t stream) {
  const float* x1      = (const float*)d_in[0];
  const float* x2      = (const float*)d_in[1];
  const float* norm1_w = (const float*)d_in[2];
  const float* norm1_b = (const float*)d_in[3];
  const float* qkv_w   = (const float*)d_in[4];
  const float* qkv_b   = (const float*)d_in[5];
  const float* poolq_w = (const float*)d_in[6];
  const float* poolk_w = (const float*)d_in[7];
  const float* poolv_w = (const float*)d_in[8];
  const float* nq_w    = (const float*)d_in[9];
  const float* nq_b    = (const float*)d_in[10];
  const float* nk_w    = (const float*)d_in[11];
  const float* nk_b    = (const float*)d_in[12];
  const float* nv_w    = (const float*)d_in[13];
  const float* nv_b    = (const float*)d_in[14];
  const float* rel_h   = (const float*)d_in[15];
  const float* rel_w   = (const float*)d_in[16];
  const float* proj_w  = (const float*)d_in[17];
  const float* proj_b  = (const float*)d_in[18];
  const float* norm2_w = (const float*)d_in[19];
  const float* norm2_b = (const float*)d_in[20];
  const float* fc1_w   = (const float*)d_in[21];
  const float* fc1_b   = (const float*)d_in[22];
  const float* fc2_w   = (const float*)d_in[23];
  const float* fc2_b   = (const float*)d_in[24];

  // ws overlay (u16 units). Peak = 57,802,752 u16 = 115.6 MB
  u16* ws      = (u16*)d_ws;
  u16* qkv     = ws;                  // [0, 28901376)   qkv bf16, [3,64,3136,48]
  u16* xn      = ws + 28901376;       // LN(x1) bf16
  u16* qkvc    = ws + 28901376;       // post conv+LN (after xn dead)
  u16* obuf    = ws;                  // attn out bf16 [B,H,W,384]
  u16* h1      = ws;                  // gelu(fc1) bf16
  u16* yn      = ws + 48168960;       // LN(y1) bf16
  u16* qkv_wt  = ws + 38535168;       // bf16 [1152][384] (dies at step 3)
  u16* proj_wt = ws + 9633792;        // bf16 [384][384]  (after qkv dead)
  u16* fc1_wt  = ws + 38535168;       // bf16 [1536][384] (after qkvc dead)
  u16* fc2_wt  = ws + 39124992;       // bf16 [384][1536]
  float* y1 = (float*)d_out;          // 9633792 f32
  float* y2 = y1 + 9633792;

  // 0a. convert qkv weights (transposed [N][K] bf16)
  wcvt_kernel<<<dim3(12, 36), 256, 0, stream>>>(qkv_w, qkv_wt, 384, 1152);
  // 1. xn = LN(x1)
  ln384_kernel<<<NTOK / 4, 256, 0, stream>>>(x1, norm1_w, norm1_b, xn);
  // 2. qkv = xn @ qkv_w + qkv_b  (MFMA, scattered layout)
  mgemm_kernel<0><<<dim3(196, 9), 256, 0, stream>>>(xn, qkv_wt, qkv_b, nullptr, qkv, NTOK, 1152, 384);
  // 3. q/k/v = LN(dwconv3x3(qkv))  (thread-per-pixel)
  convln_kernel<<<dim3(13, 192), 256, 0, stream>>>(qkv, poolq_w, poolk_w, poolv_w,
                                                   nq_w, nq_b, nk_w, nk_b, nv_w, nv_b, qkvc);
  // 0b. convert proj weights (qkv region now dead)
  wcvt_kernel<<<dim3(12, 12), 256, 0, stream>>>(proj_w, proj_wt, 384, 384);
  // 4. MFMA window attention (+ ori_q residual), permuted to [B,H,W,384]
  attn_kernel<<<1024, 512, 0, stream>>>(qkvc, rel_h, rel_w, obuf);
  // 0c. convert mlp weights (qkvc region now dead)
  wcvt_kernel<<<dim3(12, 48), 256, 0, stream>>>(fc1_w, fc1_wt, 384, 1536);
  wcvt_kernel<<<dim3(48, 12), 256, 0, stream>>>(fc2_w, fc2_wt, 1536, 384);
  // 5. y1 = x1 + obuf @ proj_w + proj_b
  mgemm_kernel<1><<<dim3(196, 3), 256, 0, stream>>>(obuf, proj_wt, proj_b, x1, y1, NTOK, 384, 384);
  // 6. yn = LN(y1)
  ln384_kernel<<<NTOK / 4, 256, 0, stream>>>(y1, norm2_w, norm2_b, yn);
  // 7. h1 = gelu(yn @ fc1_w + fc1_b)
  mgemm_kernel<2><<<dim3(196, 12), 256, 0, stream>>>(yn, fc1_wt, fc1_b, nullptr, h1, NTOK, 1536, 384);
  // 8. y2 = x2 + h1 @ fc2_w + fc2_b
  mgemm_kernel<1><<<dim3(196, 3), 256, 0, stream>>>(h1, fc2_wt, fc2_b, x2, y2, NTOK, 384, 1536);
}

// Round 9
// 374.741 us; speedup vs baseline: 5.1565x; 1.0863x over previous
//
#include <hip/hip_runtime.h>
#include <hip/hip_bf16.h>

typedef unsigned short u16;
typedef unsigned int u32;

#define DEVI __device__ __forceinline__

constexpr int BB = 8, HHc = 56, WWc = 56, DIMC = 384, NHC = 8, HDC = 48, WSZ = 14;
constexpr int NTOK = BB * HHc * WWc;          // 25088
constexpr int HIDC = 4 * DIMC;                // 1536
constexpr float EPSF = 1e-5f;
constexpr float SCALEF = 0.14433756729740643f;   // 48^-0.5

typedef short bf16x8 __attribute__((ext_vector_type(8)));
typedef float f32x4 __attribute__((ext_vector_type(4)));

// ---- bf16 helpers (raw ushort view) ----
DEVI float b2f(u16 u) { u32 x = ((u32)u) << 16; float f; __builtin_memcpy(&f, &x, 4); return f; }
DEVI float uasf(u32 x) { float f; __builtin_memcpy(&f, &x, 4); return f; }
DEVI u16 f2b(float f) {
  u32 x; __builtin_memcpy(&x, &f, 4);
  u32 r = (x >> 16) & 1u; x += 0x7fffu + r;
  return (u16)(x >> 16);
}

DEVI float wred_sum(float v) {
  #pragma unroll
  for (int o = 32; o; o >>= 1) v += __shfl_xor(v, o);
  return v;
}

// async global->LDS, 16B per lane; dest = uniform base + lane*16
#define GLOAD_LDS16(g, l) __builtin_amdgcn_global_load_lds( \
    (const __attribute__((address_space(1))) u32*)(g), \
    (__attribute__((address_space(3))) u32*)(l), 16, 0, 0)

// ---- weight convert f32 [K][N] -> bf16 [N][K], LDS-tiled transpose ----
__global__ __launch_bounds__(256)
void wcvt_kernel(const float* __restrict__ in, u16* __restrict__ out, int K, int N) {
  __shared__ float t[32][33];
  int bk = blockIdx.x * 32, bn = blockIdx.y * 32;
  int tx = threadIdx.x & 31, ty = threadIdx.x >> 5;
  #pragma unroll
  for (int i = 0; i < 32; i += 8)
    t[ty + i][tx] = in[(size_t)(bk + ty + i) * N + bn + tx];
  __syncthreads();
  #pragma unroll
  for (int i = 0; i < 32; i += 8)
    out[(size_t)(bn + ty + i) * K + bk + tx] = f2b(t[tx][ty + i]);
}

// ---- LayerNorm over 384: f32 in -> bf16 out (one wave per token) ----
__global__ __launch_bounds__(256)
void ln384_kernel(const float* __restrict__ x, const float* __restrict__ w,
                  const float* __restrict__ b, u16* __restrict__ out) {
  int wave = threadIdx.x >> 6, lane = threadIdx.x & 63;
  int tok = blockIdx.x * 4 + wave;
  if (tok >= NTOK) return;
  const float* xr = x + (size_t)tok * DIMC;
  float v[6]; float s = 0.f, ss = 0.f;
  #pragma unroll
  for (int i = 0; i < 6; ++i) {
    v[i] = xr[lane + i * 64];
    s += v[i]; ss += v[i] * v[i];
  }
  s = wred_sum(s); ss = wred_sum(ss);
  float mean = s * (1.f / 384.f);
  float var = ss * (1.f / 384.f) - mean * mean;
  float inv = rsqrtf(var + EPSF);
  u16* orow = out + (size_t)tok * DIMC;
  #pragma unroll
  for (int i = 0; i < 6; ++i) {
    int c = lane + i * 64;
    orow[c] = f2b((v[i] - mean) * inv * w[c] + b[c]);
  }
}

// ---- MFMA GEMM: C[M,N] = A(bf16)[M,K] @ Wt(bf16,[N][K])^T + bias ----
// 128x128 tile, BK=32, 4 waves; double-buffered global_load_lds(16B),
// prefetch-next-before-compute, ONE barrier per k-step.
template<int MODE>
__global__ __launch_bounds__(256)
void mgemm_kernel(const u16* __restrict__ A, const u16* __restrict__ Wt,
                  const float* __restrict__ bias, const float* __restrict__ res,
                  void* __restrict__ outv, int M, int N, int K) {
  __shared__ __attribute__((aligned(16))) u16 As[2][128 * 32];
  __shared__ __attribute__((aligned(16))) u16 Bs[2][128 * 32];
  int tid = threadIdx.x;
  int wave = tid >> 6, lane = tid & 63;
  int wr = wave >> 1, wc = wave & 1;
  int bm0 = blockIdx.x * 128, bn0 = blockIdx.y * 128;
  int lrow = lane >> 2;
  int slot = (lane & 3) ^ ((lane >> 3) & 3);
  const u16* ag0 = A  + (size_t)(bm0 + wave * 32 + lrow) * K + slot * 8;
  const u16* ag1 = ag0 + (size_t)16 * K;
  const u16* bg0 = Wt + (size_t)(bn0 + wave * 32 + lrow) * K + slot * 8;
  const u16* bg1 = bg0 + (size_t)16 * K;
  int q4 = lane >> 4, r16 = lane & 15;
  int rslot = (q4 ^ ((r16 >> 1) & 3)) * 8;        // de-swizzle on read
  int aoff = (wr * 64 + r16) * 32 + rslot;
  int boff = (wc * 64 + r16) * 32 + rslot;
  f32x4 acc[4][4] = {};
  int nk = K >> 5;
  {  // prologue: stage t=0 into buf 0
    u16* a0 = As[0] + wave * 1024;
    u16* b0 = Bs[0] + wave * 1024;
    GLOAD_LDS16(ag0, a0);
    GLOAD_LDS16(ag1, a0 + 512);
    GLOAD_LDS16(bg0, b0);
    GLOAD_LDS16(bg1, b0 + 512);
  }
  __syncthreads();
  int cur = 0;
  for (int t = 0; t < nk; ++t) {
    if (t + 1 < nk) {                              // prefetch next tile (async)
      int k0 = (t + 1) << 5;
      u16* a0 = As[cur ^ 1] + wave * 1024;
      u16* b0 = Bs[cur ^ 1] + wave * 1024;
      GLOAD_LDS16(ag0 + k0, a0);
      GLOAD_LDS16(ag1 + k0, a0 + 512);
      GLOAD_LDS16(bg0 + k0, b0);
      GLOAD_LDS16(bg1 + k0, b0 + 512);
    }
    const u16* ar = As[cur] + aoff;
    const u16* br = Bs[cur] + boff;
    bf16x8 af[4], bf[4];
    #pragma unroll
    for (int f = 0; f < 4; ++f) {
      af[f] = *reinterpret_cast<const bf16x8*>(ar + f * 512);
      bf[f] = *reinterpret_cast<const bf16x8*>(br + f * 512);
    }
    #pragma unroll
    for (int fm = 0; fm < 4; ++fm)
      #pragma unroll
      for (int fn = 0; fn < 4; ++fn)
        acc[fm][fn] = __builtin_amdgcn_mfma_f32_16x16x32_bf16(af[fm], bf[fn], acc[fm][fn], 0, 0, 0);
    __syncthreads();
    cur ^= 1;
  }
  int c0 = bn0 + wc * 64 + r16;
  int r0 = bm0 + wr * 64 + q4 * 4;
  #pragma unroll
  for (int fm = 0; fm < 4; ++fm) {
    #pragma unroll
    for (int fn = 0; fn < 4; ++fn) {
      int c = c0 + fn * 16;
      float bsv = bias[c];
      #pragma unroll
      for (int j = 0; j < 4; ++j) {
        int r = r0 + fm * 16 + j;
        float v = acc[fm][fn][j] + bsv;
        if constexpr (MODE == 0) {
          u16* out = (u16*)outv;
          int s = c / DIMC; int rem = c - s * DIMC;
          int nh = rem / HDC; int ch = rem - nh * HDC;
          int b = r / 3136; int hw = r - b * 3136;
          out[(((size_t)(s * 64 + b * 8 + nh)) * 3136 + hw) * 48 + ch] = f2b(v);
        } else if constexpr (MODE == 1) {
          float* out = (float*)outv;
          size_t idx = (size_t)r * N + c;
          out[idx] = v + res[idx];
        } else {
          u16* out = (u16*)outv;
          size_t idx = (size_t)r * N + c;
          out[idx] = f2b(0.5f * v * (1.0f + erff(v * 0.70710678118654752440f)));
        }
      }
    }
  }
}

// ---- depthwise 3x3 conv (pad 1) + LayerNorm over 48 channels ----
__global__ __launch_bounds__(256)
void convln_kernel(const u16* __restrict__ qkv,
                   const float* __restrict__ wq, const float* __restrict__ wk, const float* __restrict__ wv,
                   const float* __restrict__ gq, const float* __restrict__ bq,
                   const float* __restrict__ gk, const float* __restrict__ bk,
                   const float* __restrict__ gv, const float* __restrict__ bv,
                   u16* __restrict__ out) {
  __shared__ __attribute__((aligned(16))) float wsm[432];
  __shared__ __attribute__((aligned(16))) float gsm[48];
  __shared__ __attribute__((aligned(16))) float bsm[48];
  int tid = threadIdx.x;
  int sb = blockIdx.y;                  // 0..191 = s*64 + bnh
  int s = sb >> 6;
  const float* wgt = (s == 0) ? wq : ((s == 1) ? wk : wv);
  const float* gam = (s == 0) ? gq : ((s == 1) ? gk : gv);
  const float* bet = (s == 0) ? bq : ((s == 1) ? bk : bv);
  for (int i = tid; i < 432; i += 256) wsm[i] = wgt[i];
  if (tid < 48) { gsm[tid] = gam[tid]; bsm[tid] = bet[tid]; }
  __syncthreads();
  int hw = blockIdx.x * 256 + tid;
  if (hw >= 3136) return;
  int h = hw / 56, w = hw - h * 56;
  const u16* img = qkv + (size_t)sb * (3136 * 48);
  float acc[48];
  #pragma unroll
  for (int c = 0; c < 48; ++c) acc[c] = 0.f;
  #pragma unroll
  for (int dy = -1; dy <= 1; ++dy) {
    int hh = h + dy;
    if ((unsigned)hh >= 56u) continue;
    #pragma unroll
    for (int dx = -1; dx <= 1; ++dx) {
      int ww = w + dx;
      if ((unsigned)ww >= 56u) continue;
      const uint4* p = reinterpret_cast<const uint4*>(img + (size_t)(hh * 56 + ww) * 48);
      const float4* wr = reinterpret_cast<const float4*>(wsm + ((dy + 1) * 3 + (dx + 1)) * 48);
      #pragma unroll
      for (int g = 0; g < 6; ++g) {
        uint4 v = p[g];
        float4 w0 = wr[g * 2], w1 = wr[g * 2 + 1];
        acc[g * 8 + 0] += uasf(v.x << 16)          * w0.x;
        acc[g * 8 + 1] += uasf(v.x & 0xFFFF0000u)  * w0.y;
        acc[g * 8 + 2] += uasf(v.y << 16)          * w0.z;
        acc[g * 8 + 3] += uasf(v.y & 0xFFFF0000u)  * w0.w;
        acc[g * 8 + 4] += uasf(v.z << 16)          * w1.x;
        acc[g * 8 + 5] += uasf(v.z & 0xFFFF0000u)  * w1.y;
        acc[g * 8 + 6] += uasf(v.w << 16)          * w1.z;
        acc[g * 8 + 7] += uasf(v.w & 0xFFFF0000u)  * w1.w;
      }
    }
  }
  float sum = 0.f, ssq = 0.f;
  #pragma unroll
  for (int c = 0; c < 48; ++c) { sum += acc[c]; ssq += acc[c] * acc[c]; }
  float mean = sum * (1.f / 48.f);
  float var = ssq * (1.f / 48.f) - mean * mean;
  float inv = rsqrtf(var + EPSF);
  u16* op = out + ((size_t)sb * 3136 + hw) * 48;
  #pragma unroll
  for (int g = 0; g < 6; ++g) {
    const float4 gm0 = *reinterpret_cast<const float4*>(gsm + g * 8);
    const float4 gm1 = *reinterpret_cast<const float4*>(gsm + g * 8 + 4);
    const float4 bt0 = *reinterpret_cast<const float4*>(bsm + g * 8);
    const float4 bt1 = *reinterpret_cast<const float4*>(bsm + g * 8 + 4);
    uint4 ov;
    u32 a0 = f2b((acc[g * 8 + 0] - mean) * inv * gm0.x + bt0.x);
    u32 a1 = f2b((acc[g * 8 + 1] - mean) * inv * gm0.y + bt0.y);
    u32 a2 = f2b((acc[g * 8 + 2] - mean) * inv * gm0.z + bt0.z);
    u32 a3 = f2b((acc[g * 8 + 3] - mean) * inv * gm0.w + bt0.w);
    u32 a4 = f2b((acc[g * 8 + 4] - mean) * inv * gm1.x + bt1.x);
    u32 a5 = f2b((acc[g * 8 + 5] - mean) * inv * gm1.y + bt1.y);
    u32 a6 = f2b((acc[g * 8 + 6] - mean) * inv * gm1.z + bt1.z);
    u32 a7 = f2b((acc[g * 8 + 7] - mean) * inv * gm1.w + bt1.w);
    ov.x = a0 | (a1 << 16);
    ov.y = a2 | (a3 << 16);
    ov.z = a4 | (a5 << 16);
    ov.w = a6 | (a7 << 16);
    *reinterpret_cast<uint4*>(op + g * 8) = ov;
  }
}

// ---- MFMA window attention, extended-K bias fold ----
// Extended k-dim = 96: cols 0..47 = K data (pre-scaled); 48..61 one-hot(kh);
// 62..75 one-hot(kw); 76 pad-flag; 77..95 zero. Q-side cols 48..95 come from
// QE LDS: gathered bh/bw tables + (-30000) mask coeff + zeros.
// LDS: KL[208][104], VT[48][228], QE[208][56], PB = Rel staging / 8 P-tiles.
#define MFMA16(a, b, c) __builtin_amdgcn_mfma_f32_16x16x32_bf16((a), (b), (c), 0, 0, 0)
constexpr int LDP = 224;
constexpr int LDK = 104;
constexpr int LDV = 228;
__global__ __launch_bounds__(512, 1)
void attn_kernel(const u16* __restrict__ qkvc, const float* __restrict__ rel_h,
                 const float* __restrict__ rel_w, u16* __restrict__ obuf) {
  __shared__ __attribute__((aligned(16))) u16 KL[208 * LDK];
  __shared__ __attribute__((aligned(16))) u16 VT[48 * LDV];
  __shared__ __attribute__((aligned(16))) u16 QE[208 * 56];
  __shared__ __attribute__((aligned(16))) u16 PB[8 * 16 * LDP];

  int wid = blockIdx.x;
  int bnh = wid >> 4, wrem = wid & 15, wh = wrem >> 2, wwn = wrem & 3;
  int tid = threadIdx.x;
  int wave = tid >> 6, lane = tid & 63;
  int q4 = lane >> 4, r16 = lane & 15;

  { u32* z;
    z = (u32*)KL; for (int i = tid; i < 208 * LDK / 2; i += 512) z[i] = 0;
    z = (u32*)VT; for (int i = tid; i < 48 * LDV / 2; i += 512) z[i] = 0;
    // QRW B-operand reads PB rows 0..63 x cols 0..63 (stride 72). LDS start
    // state is UNDEFINED; a NaN bit-pattern there poisons the MFMA even
    // against a zero A-operand (0*NaN=NaN) -> must zero the region.
    z = (u32*)PB; for (int i = tid; i < 64 * 72 / 2; i += 512) z[i] = 0;
  }
  __syncthreads();
  size_t qbase = (size_t)bnh * 3136 * 48;
  size_t kbase = ((size_t)(64 + bnh) * 3136) * 48;
  size_t vbase = ((size_t)(128 + bnh) * 3136) * 48;
  for (int i = tid; i < 196 * 12; i += 512) {
    int r = i / 12, c4 = (i - r * 12) * 4;
    int h = wh * 14 + r / 14, w = wwn * 14 + r % 14;
    size_t g = (size_t)(h * 56 + w) * 48 + c4;
    ushort4 kv = *reinterpret_cast<const ushort4*>(qkvc + kbase + g);
    kv.x = f2b(b2f(kv.x) * SCALEF); kv.y = f2b(b2f(kv.y) * SCALEF);
    kv.z = f2b(b2f(kv.z) * SCALEF); kv.w = f2b(b2f(kv.w) * SCALEF);
    *reinterpret_cast<ushort4*>(KL + r * LDK + c4) = kv;
    ushort4 vv = *reinterpret_cast<const ushort4*>(qkvc + vbase + g);
    VT[(c4 + 0) * LDV + r] = vv.x; VT[(c4 + 1) * LDV + r] = vv.y;
    VT[(c4 + 2) * LDV + r] = vv.z; VT[(c4 + 3) * LDV + r] = vv.w;
  }
  // K one-hot / mask flag columns (bf16 1.0 = 0x3F80)
  for (int r = tid; r < 208; r += 512) {
    if (r < 196) {
      KL[r * LDK + 48 + r / 14] = 0x3F80;
      KL[r * LDK + 62 + r % 14] = 0x3F80;
    } else {
      KL[r * LDK + 76] = 0x3F80;
    }
  }
  // Rel staging into PB rows 0..53 (stride 72): rows 0..26 Rh, 27..53 Rw
  for (int i = tid; i < 54 * 48; i += 512) {
    int r = i / 48, c = i - r * 48;
    float v = (r < 27) ? rel_h[r * 48 + c] : rel_w[(r - 27) * 48 + c];
    PB[r * 72 + c] = f2b(v);
  }
  __syncthreads();
  // QE = Q @ Rel^T  (cols 0..53; Q from global, clamp pad rows; k 48..63 zeroed)
  for (int mf = wave; mf < 13; mf += 8) {
    int qrow = mf * 16 + r16; int qc = qrow < 196 ? qrow : 195;
    int hq = wh * 14 + qc / 14, wq = wwn * 14 + qc % 14;
    const u16* qpg = qkvc + qbase + (size_t)(hq * 56 + wq) * 48;
    bf16x8 af0 = *reinterpret_cast<const bf16x8*>(qpg + q4 * 8);
    bf16x8 af1 = {0, 0, 0, 0, 0, 0, 0, 0};
    if (q4 < 2) af1 = *reinterpret_cast<const bf16x8*>(qpg + 32 + q4 * 8);
    #pragma unroll
    for (int nf = 0; nf < 4; ++nf) {
      bf16x8 b0 = *reinterpret_cast<const bf16x8*>(PB + (nf * 16 + r16) * 72 + q4 * 8);
      bf16x8 b1 = *reinterpret_cast<const bf16x8*>(PB + (nf * 16 + r16) * 72 + 32 + q4 * 8);
      f32x4 acc = {};
      acc = MFMA16(af0, b0, acc);
      acc = MFMA16(af1, b1, acc);
      int col = nf * 16 + r16;
      if (col < 54) {
        #pragma unroll
        for (int j = 0; j < 4; ++j)
          QE[(mf * 16 + q4 * 4 + j) * 56 + col] = f2b(acc[j]);
      }
    }
  }
  __syncthreads();
  // in-place gather: QE[row][z]=bh(z), [14+z]=bw(z), [28]=-30000, [29..55]=0
  u16 bhv[14], bwv[14];
  {
    int t = tid;
    if (t < 208) {
      int qc = t < 196 ? t : 195;
      int qh = qc / 14, qw = qc - qh * 14;
      const u16* src = QE + t * 56;
      #pragma unroll
      for (int z = 0; z < 14; ++z) {
        bhv[z] = src[qh + 13 - z];
        bwv[z] = src[27 + qw + 13 - z];
      }
    }
  }
  __syncthreads();
  {
    int t = tid;
    if (t < 208) {
      u16* dst = QE + t * 56;
      #pragma unroll
      for (int z = 0; z < 14; ++z) { dst[z] = bhv[z]; dst[14 + z] = bwv[z]; }
      dst[28] = f2b(-30000.0f);
      #pragma unroll
      for (int z = 29; z < 56; ++z) dst[z] = 0;
    }
  }
  // zero this wave's P-tile pad slots (swizzled positions)
  u16* Pw = PB + wave * 16 * LDP;
  for (int i = lane; i < 16 * 16; i += 64) {
    int r = i >> 4;
    Pw[r * LDP + ((208 + (i & 15)) ^ (((r >> 2) & 3) << 3))] = 0;
  }
  __syncthreads();
  int bI = bnh >> 3, nhI = bnh & 7;
  // ---- main loop: per wave, no barriers ----
  for (int mf = wave; mf < 13; mf += 8) {
    int qrow = mf * 16 + r16; int qc = qrow < 196 ? qrow : 195;
    int hq = wh * 14 + qc / 14, wq = wwn * 14 + qc % 14;
    const u16* qpg = qkvc + qbase + (size_t)(hq * 56 + wq) * 48;
    const u16* qe = QE + qrow * 56;
    bf16x8 af0 = *reinterpret_cast<const bf16x8*>(qpg + q4 * 8);
    bf16x8 af1;
    if (q4 < 2) af1 = *reinterpret_cast<const bf16x8*>(qpg + 32 + q4 * 8);
    else        af1 = *reinterpret_cast<const bf16x8*>(qe + (q4 - 2) * 8);
    bf16x8 af2 = *reinterpret_cast<const bf16x8*>(qe + 16 + q4 * 8);
    f32x4 s[13];
    #pragma unroll
    for (int nf = 0; nf < 13; ++nf) {
      const u16* kr = KL + (nf * 16 + r16) * LDK;
      bf16x8 b0 = *reinterpret_cast<const bf16x8*>(kr + q4 * 8);
      bf16x8 b1 = *reinterpret_cast<const bf16x8*>(kr + 32 + q4 * 8);
      bf16x8 b2 = *reinterpret_cast<const bf16x8*>(kr + 64 + q4 * 8);
      f32x4 a = {};
      a = MFMA16(af0, b0, a);
      a = MFMA16(af1, b1, a);
      a = MFMA16(af2, b2, a);
      s[nf] = a;
    }
    int rowb = mf * 16 + q4 * 4;
    float mrow[4], den[4];
    #pragma unroll
    for (int j = 0; j < 4; ++j) {
      float mm = s[0][j];
      #pragma unroll
      for (int nf = 1; nf < 13; ++nf) mm = fmaxf(mm, s[nf][j]);
      #pragma unroll
      for (int off = 1; off < 16; off <<= 1) mm = fmaxf(mm, __shfl_xor(mm, off));
      mrow[j] = mm; den[j] = 0.f;
    }
    #pragma unroll
    for (int nf = 0; nf < 13; ++nf) {
      #pragma unroll
      for (int j = 0; j < 4; ++j) {
        float p = __expf(s[nf][j] - mrow[j]);
        den[j] += p;
        Pw[(q4 * 4 + j) * LDP + (((nf * 16 + r16) ^ (q4 << 3)))] = f2b(p);
      }
    }
    #pragma unroll
    for (int j = 0; j < 4; ++j)
      #pragma unroll
      for (int off = 1; off < 16; off <<= 1) den[j] += __shfl_xor(den[j], off);
    f32x4 o[3] = {};
    #pragma unroll
    for (int ks = 0; ks < 7; ++ks) {
      bf16x8 ap = *reinterpret_cast<const bf16x8*>(
          Pw + r16 * LDP + ((ks * 32 + q4 * 8) ^ (((r16 >> 2) & 3) << 3)));
      #pragma unroll
      for (int nf3 = 0; nf3 < 3; ++nf3) {
        bf16x8 bv = *reinterpret_cast<const bf16x8*>(VT + (nf3 * 16 + r16) * LDV + ks * 32 + q4 * 8);
        o[nf3] = MFMA16(ap, bv, o[nf3]);
      }
    }
    #pragma unroll
    for (int j = 0; j < 4; ++j) {
      int row = rowb + j;
      if (row < 196) {
        float rden = 1.f / den[j];
        int rh = row / 14;
        int h = wh * 14 + rh, w = wwn * 14 + row - rh * 14;
        const u16* qg = qkvc + qbase + (size_t)(h * 56 + w) * 48;
        u16* op = obuf + ((size_t)(bI * 56 + h) * 56 + w) * 384 + nhI * 48;
        #pragma unroll
        for (int nf3 = 0; nf3 < 3; ++nf3) {
          int col = nf3 * 16 + r16;
          op[col] = f2b(o[nf3][j] * rden + b2f(qg[col]));
        }
      }
    }
  }
}

extern "C" void kernel_launch(void* const* d_in, const int* in_sizes, int n_in,
                              void* d_out, int out_size, void* d_ws, size_t ws_size,
                              hipStream_t stream) {
  const float* x1      = (const float*)d_in[0];
  const float* x2      = (const float*)d_in[1];
  const float* norm1_w = (const float*)d_in[2];
  const float* norm1_b = (const float*)d_in[3];
  const float* qkv_w   = (const float*)d_in[4];
  const float* qkv_b   = (const float*)d_in[5];
  const float* poolq_w = (const float*)d_in[6];
  const float* poolk_w = (const float*)d_in[7];
  const float* poolv_w = (const float*)d_in[8];
  const float* nq_w    = (const float*)d_in[9];
  const float* nq_b    = (const float*)d_in[10];
  const float* nk_w    = (const float*)d_in[11];
  const float* nk_b    = (const float*)d_in[12];
  const float* nv_w    = (const float*)d_in[13];
  const float* nv_b    = (const float*)d_in[14];
  const float* rel_h   = (const float*)d_in[15];
  const float* rel_w   = (const float*)d_in[16];
  const float* proj_w  = (const float*)d_in[17];
  const float* proj_b  = (const float*)d_in[18];
  const float* norm2_w = (const float*)d_in[19];
  const float* norm2_b = (const float*)d_in[20];
  const float* fc1_w   = (const float*)d_in[21];
  const float* fc1_b   = (const float*)d_in[22];
  const float* fc2_w   = (const float*)d_in[23];
  const float* fc2_b   = (const float*)d_in[24];

  // ws overlay (u16 units). Peak = 57,802,752 u16 = 115.6 MB
  u16* ws      = (u16*)d_ws;
  u16* qkv     = ws;                  // [0, 28901376)   qkv bf16, [3,64,3136,48]
  u16* xn      = ws + 28901376;       // LN(x1) bf16
  u16* qkvc    = ws + 28901376;       // post conv+LN (after xn dead)
  u16* obuf    = ws;                  // attn out bf16 [B,H,W,384]
  u16* h1      = ws;                  // gelu(fc1) bf16
  u16* yn      = ws + 48168960;       // LN(y1) bf16
  u16* qkv_wt  = ws + 38535168;       // bf16 [1152][384] (dies at step 3)
  u16* proj_wt = ws + 9633792;        // bf16 [384][384]  (after qkv dead)
  u16* fc1_wt  = ws + 38535168;       // bf16 [1536][384] (after qkvc dead)
  u16* fc2_wt  = ws + 39124992;       // bf16 [384][1536]
  float* y1 = (float*)d_out;          // 9633792 f32
  float* y2 = y1 + 9633792;

  // 0a. convert qkv weights (transposed [N][K] bf16)
  wcvt_kernel<<<dim3(12, 36), 256, 0, stream>>>(qkv_w, qkv_wt, 384, 1152);
  // 1. xn = LN(x1)
  ln384_kernel<<<NTOK / 4, 256, 0, stream>>>(x1, norm1_w, norm1_b, xn);
  // 2. qkv = xn @ qkv_w + qkv_b  (MFMA, scattered layout)
  mgemm_kernel<0><<<dim3(196, 9), 256, 0, stream>>>(xn, qkv_wt, qkv_b, nullptr, qkv, NTOK, 1152, 384);
  // 3. q/k/v = LN(dwconv3x3(qkv))  (thread-per-pixel)
  convln_kernel<<<dim3(13, 192), 256, 0, stream>>>(qkv, poolq_w, poolk_w, poolv_w,
                                                   nq_w, nq_b, nk_w, nk_b, nv_w, nv_b, qkvc);
  // 0b. convert proj weights (qkv region now dead)
  wcvt_kernel<<<dim3(12, 12), 256, 0, stream>>>(proj_w, proj_wt, 384, 384);
  // 4. MFMA window attention (+ ori_q residual), permuted to [B,H,W,384]
  attn_kernel<<<1024, 512, 0, stream>>>(qkvc, rel_h, rel_w, obuf);
  // 0c. convert mlp weights (qkvc region now dead)
  wcvt_kernel<<<dim3(12, 48), 256, 0, stream>>>(fc1_w, fc1_wt, 384, 1536);
  wcvt_kernel<<<dim3(48, 12), 256, 0, stream>>>(fc2_w, fc2_wt, 1536, 384);
  // 5. y1 = x1 + obuf @ proj_w + proj_b
  mgemm_kernel<1><<<dim3(196, 3), 256, 0, stream>>>(obuf, proj_wt, proj_b, x1, y1, NTOK, 384, 384);
  // 6. yn = LN(y1)
  ln384_kernel<<<NTOK / 4, 256, 0, stream>>>(y1, norm2_w, norm2_b, yn);
  // 7. h1 = gelu(yn @ fc1_w + fc1_b)
  mgemm_kernel<2><<<dim3(196, 12), 256, 0, stream>>>(yn, fc1_wt, fc1_b, nullptr, h1, NTOK, 1536, 384);
  // 8. y2 = x2 + h1 @ fc2_w + fc2_b
  mgemm_kernel<1><<<dim3(196, 3), 256, 0, stream>>>(h1, fc2_wt, fc2_b, x2, y2, NTOK, 384, 1536);
}